// Round 1
// 2127.030 us; speedup vs baseline: 1.0366x; 1.0366x over previous
//
#include <hip/hip_runtime.h>
#include <math.h>

// ---------------------------------------------------------------------------
// MultiLevelGlobalContext — bf16 MFMA + global_load_lds dbuf + XCD swizzle +
// stacked dual-output GEMMs.
// Levels: ci={256,512,1024,2048}, hw={10000,2500,625,169}, ni={256,192,128,64}
// B=8, C=256, G=640.
// ---------------------------------------------------------------------------

#define BB 8
#define CC 256
#define GG 640

typedef __attribute__((ext_vector_type(8))) short short8;
typedef __attribute__((ext_vector_type(4))) float f32x4;

__device__ __forceinline__ unsigned short f2bf(float f) {
    unsigned int u = __float_as_uint(f);
    u += 0x7fffu + ((u >> 16) & 1u);
    return (unsigned short)(u >> 16);
}
__device__ __forceinline__ float bf2f(unsigned short h) {
    return __uint_as_float(((unsigned int)h) << 16);
}
__device__ __forceinline__ float h2f(unsigned short h) {
    union { unsigned short u; _Float16 x; } cv; cv.u = h; return (float)cv.x;
}
__device__ __forceinline__ unsigned short f2h(float f) {
    union { unsigned short u; _Float16 x; } cv; cv.x = (_Float16)f; return cv.u;
}

// async global -> LDS, 16B per lane (wave-uniform LDS base + lane*16 layout)
__device__ __forceinline__ void glds16(const unsigned short* g, unsigned short* l) {
    __builtin_amdgcn_global_load_lds(
        (const __attribute__((address_space(1))) void*)g,
        (__attribute__((address_space(3))) void*)l, 16, 0, 0);
}

// ===================== bf16 MFMA GEMM: C[b] = A(M,K) @ B(N,K)^T =============
// A, B bf16 (ushort), K contiguous.  Direct-to-LDS double buffer, 1 barrier
// per K-step.  1-D grid with XCD-chunked bijective swizzle; ordering puts the
// blocks sharing the LARGE operand's tiles adjacent (same XCD -> L2 hit).
// modes: 0 store f32, 1 accum f32, 2 atomicAdd f32, 3 store f16, 4 store bf16
// Segmented epilogue: rows [0,M1) -> C/mode, rows [M1,M) -> C2/mode2.
__global__ __launch_bounds__(256) void mfmaGemm(
    const unsigned short* __restrict__ A, long sA, int lda,
    const unsigned short* __restrict__ B, long sB, int ldb,
    void* __restrict__ C, long sC, int ldc, long offC,
    int M, int N, int K, int kChunks, int kChunkLen, int mode,
    int gxn, int gym,
    void* __restrict__ C2, long sC2, int ldc2, long offC2, int M1, int mode2)
{
    __shared__ __align__(16) unsigned short As[2][128 * 32];
    __shared__ __align__(16) unsigned short Bs[2][128 * 32];

    // ---- XCD-chunked bijective swizzle (each XCD gets a contiguous chunk) --
    const int nb = (int)gridDim.x;
    int orig = (int)blockIdx.x;
    int xcd = orig & 7, idx = orig >> 3;
    int q8 = nb >> 3, r8 = nb & 7;
    int wg = (xcd < r8) ? (xcd * (q8 + 1) + idx)
                        : (r8 * (q8 + 1) + (xcd - r8) * q8 + idx);
    int mb, nbk, z;
    if (N >= M) { mb = wg % gym; int t = wg / gym; nbk = t % gxn; z = t / gxn; }
    else        { nbk = wg % gxn; int t = wg / gxn; mb = t % gym; z = t / gym; }

    const int b = z / kChunks, chunk = z - b * kChunks;
    const int kbeg = chunk * kChunkLen;
    const int kend = min(K, kbeg + kChunkLen);
    const int m0 = mb * 128, n0 = nbk * 128;

    const unsigned short* Ab = A + (long)b * sA;
    const unsigned short* Bb = B + (long)b * sB;

    const int tid = threadIdx.x;
    const int row = tid >> 2, seg = tid & 3;      // staging: row 0..63, 8-elem seg
    const int wave = tid >> 6, lane = tid & 63;
    const int wm = (wave & 1) * 64, wn = (wave >> 1) * 64;
    const int lm = lane & 15, kq = lane >> 4;

    const bool okA = ((lda & 7) == 0) && ((((size_t)Ab) & 15) == 0);
    const bool okB = ((ldb & 7) == 0) && ((((size_t)Bb) & 15) == 0);

    f32x4 acc[4][4];
    #pragma unroll
    for (int i = 0; i < 4; ++i)
        #pragma unroll
        for (int j = 0; j < 4; ++j) acc[i][j] = (f32x4){0.f, 0.f, 0.f, 0.f};

    // fast: direct global->LDS (rows may over-read; epilogue masks those rows)
    auto stageF = [&](const unsigned short* Pb, int ld, int o0,
                      unsigned short* LS, int kg) {
        #pragma unroll
        for (int l = 0; l < 2; ++l) {
            const unsigned short* src = Pb + (long)(o0 + l * 64 + row) * ld + kg + seg * 8;
            glds16(src, &LS[(l * 64 + row) * 32 + seg * 8]);
        }
    };
    // slow: reg roundtrip with zero-fill (unaligned ld / k-tail / row OOB)
    auto stageS = [&](const unsigned short* Pb, int ld, int lim, int o0,
                      unsigned short* LS, int kg) {
        int kgg = kg + seg * 8;
        int krem = kend - kgg;
        #pragma unroll
        for (int l = 0; l < 2; ++l) {
            int g = o0 + l * 64 + row;
            uint4 v = make_uint4(0u, 0u, 0u, 0u);
            if (g < lim && krem > 0) {
                const unsigned short* src = Pb + (long)g * ld + kgg;
                if (krem >= 8 && ((((size_t)src) & 15) == 0)) {
                    v = *(const uint4*)src;
                } else {
                    __align__(16) unsigned short tmp[8] = {0,0,0,0,0,0,0,0};
                    int c = krem < 8 ? krem : 8;
                    for (int j = 0; j < c; ++j) tmp[j] = src[j];
                    v = *(const uint4*)tmp;
                }
            }
            *(uint4*)&LS[(l * 64 + row) * 32 + seg * 8] = v;
        }
    };
    auto stage = [&](int kg, int buf) {
        bool full = (kg + 32 <= kend);
        if (okA && full) stageF(Ab, lda, m0, As[buf], kg);
        else             stageS(Ab, lda, M, m0, As[buf], kg);
        if (okB && full) stageF(Bb, ldb, n0, Bs[buf], kg);
        else             stageS(Bb, ldb, N, n0, Bs[buf], kg);
    };

    stage(kbeg, 0);
    int cur = 0;
    for (int k0 = kbeg; k0 < kend; k0 += 32) {
        __syncthreads();                       // drains own vmcnt/lgkmcnt -> buf[cur] ready
        if (k0 + 32 < kend) stage(k0 + 32, cur ^ 1);   // prefetch in flight during MFMA

        short8 af[4], bfr[4];
        #pragma unroll
        for (int mt = 0; mt < 4; ++mt)
            af[mt] = *(const short8*)&As[cur][(wm + mt * 16 + lm) * 32 + kq * 8];
        #pragma unroll
        for (int nt = 0; nt < 4; ++nt)
            bfr[nt] = *(const short8*)&Bs[cur][(wn + nt * 16 + lm) * 32 + kq * 8];
        #pragma unroll
        for (int mt = 0; mt < 4; ++mt)
            #pragma unroll
            for (int nt = 0; nt < 4; ++nt)
                acc[mt][nt] = __builtin_amdgcn_mfma_f32_16x16x32_bf16(
                    af[mt], bfr[nt], acc[mt][nt], 0, 0, 0);
        cur ^= 1;
    }

    const long cb1 = (long)b * sC + offC;
    const long cb2 = (long)b * sC2 + offC2;
    #pragma unroll
    for (int mt = 0; mt < 4; ++mt) {
        #pragma unroll
        for (int nt = 0; nt < 4; ++nt) {
            int n_g = n0 + wn + nt * 16 + lm;
            if (n_g >= N) continue;
            #pragma unroll
            for (int r = 0; r < 4; ++r) {
                int m_g = m0 + wm + mt * 16 + kq * 4 + r;
                if (m_g >= M) continue;
                float v = acc[mt][nt][r];
                void* Cp; int md; long cix;
                if (m_g < M1) { Cp = C;  md = mode;  cix = cb1 + (long)m_g * ldc + n_g; }
                else          { Cp = C2; md = mode2; cix = cb2 + (long)(m_g - M1) * ldc2 + n_g; }
                if (md == 0)      ((float*)Cp)[cix] = v;
                else if (md == 1) ((float*)Cp)[cix] += v;
                else if (md == 2) atomicAdd(&((float*)Cp)[cix], v);
                else if (md == 3) ((unsigned short*)Cp)[cix] = f2h(v);
                else              ((unsigned short*)Cp)[cix] = f2bf(v);
            }
        }
    }
}

// ================= fp32 GEMM (GCN layers), with optional per-level fusing ==
__global__ __launch_bounds__(256) void gemmA(
    const float* __restrict__ W, long sW,
    const float* __restrict__ X, long sX, int ldx, long offX,
    float* __restrict__ Cd, long sC, int ldc, long offC,
    const float* __restrict__ bias,
    const float* __restrict__ res, long sR, int ldr, long offR,
    int O, int K, int P, int relu, int accum,
    int lvlFuse, long wStride, int bStride)
{
    __shared__ float Ws[16][64];
    __shared__ float Xs[16][64];
    const int tid = threadIdx.x;
    const int tx = tid & 15;
    const int ty = tid >> 4;
    const int b  = blockIdx.z;
    const int o0 = blockIdx.y * 64;
    const int p0 = blockIdx.x * 64;

    const float* Wp = W;
    const float* bp = bias;
    if (lvlFuse) {
        int lvl = p0 >= 576 ? 3 : p0 >= 448 ? 2 : p0 >= 256 ? 1 : 0;
        Wp += (long)lvl * wStride;
        if (bias) bp += (long)lvl * bStride;
    }
    const float* Wb = Wp + (long)b * sW;
    const float* Xb = X + (long)b * sX + offX;

    float acc[4][4] = {};

    const int wo = tid >> 2;
    const int wk = (tid & 3) * 4;
    const int xp = tid & 63;
    const int xq = tid >> 6;

    for (int k0 = 0; k0 < K; k0 += 16) {
        #pragma unroll
        for (int u = 0; u < 4; ++u) {
            int kk = wk + u;
            float v = 0.f;
            if (o0 + wo < O && k0 + kk < K) v = Wb[(long)(o0 + wo) * K + k0 + kk];
            Ws[kk][wo] = v;
        }
        #pragma unroll
        for (int u = 0; u < 4; ++u) {
            int kk = xq * 4 + u;
            float v = 0.f;
            if (p0 + xp < P && k0 + kk < K) v = Xb[(long)(k0 + kk) * ldx + (p0 + xp)];
            Xs[kk][xp] = v;
        }
        __syncthreads();
        #pragma unroll
        for (int kk = 0; kk < 16; ++kk) {
            float4 wv = *(const float4*)&Ws[kk][ty * 4];
            float4 xv = *(const float4*)&Xs[kk][tx * 4];
            float wa[4] = {wv.x, wv.y, wv.z, wv.w};
            float xa[4] = {xv.x, xv.y, xv.z, xv.w};
            #pragma unroll
            for (int i = 0; i < 4; ++i)
                #pragma unroll
                for (int j = 0; j < 4; ++j)
                    acc[i][j] += wa[i] * xa[j];
        }
        __syncthreads();
    }

    #pragma unroll
    for (int i = 0; i < 4; ++i) {
        int o = o0 + ty * 4 + i;
        if (o >= O) continue;
        #pragma unroll
        for (int j = 0; j < 4; ++j) {
            int p = p0 + tx * 4 + j;
            if (p >= P) continue;
            float v = acc[i][j];
            if (bias) v += bp[o];
            if (relu) v = fmaxf(v, 0.f);
            if (res)  v += res[(long)b * sR + offR + (long)o * ldr + p];
            long ci_ = (long)b * sC + offC + (long)o * ldc + p;
            if (accum) Cd[ci_] += v; else Cd[ci_] = v;
        }
    }
}

// =================== transpose+convert: dst[c][r] = src[r][c]*scale[c] =====
__global__ __launch_bounds__(256) void transCvtF(
    const float* __restrict__ src, long sS, int R, int Cc,
    unsigned short* __restrict__ dst, long sD,
    const float* __restrict__ scale, long sScale)
{
    __shared__ float tile[32][33];
    int b = blockIdx.z;
    int r0 = blockIdx.y * 32, c0 = blockIdx.x * 32;
    const float* sb = src + (long)b * sS;
    unsigned short* db = dst + (long)b * sD;
    int tr = threadIdx.x >> 5, tc = threadIdx.x & 31;
    #pragma unroll
    for (int it = 0; it < 4; ++it) {
        int r = r0 + tr + it * 8, c = c0 + tc;
        tile[tr + it * 8][tc] = (r < R && c < Cc) ? sb[(long)r * Cc + c] : 0.f;
    }
    __syncthreads();
    #pragma unroll
    for (int it = 0; it < 4; ++it) {
        int c = c0 + tr + it * 8;
        int r = r0 + tc;
        if (c < Cc && r < R) {
            float v = tile[tc][tr + it * 8];
            if (scale) v *= scale[(long)b * sScale + c];
            db[(long)c * R + r] = f2bf(v);
        }
    }
}

__global__ __launch_bounds__(256) void transCvtH(
    const unsigned short* __restrict__ src, long sS, int R, int Cc,
    unsigned short* __restrict__ dst, long sD,
    const float* __restrict__ scale, long sScale)
{
    __shared__ float tile[32][33];
    int b = blockIdx.z;
    int r0 = blockIdx.y * 32, c0 = blockIdx.x * 32;
    const unsigned short* sb = src + (long)b * sS;
    unsigned short* db = dst + (long)b * sD;
    int tr = threadIdx.x >> 5, tc = threadIdx.x & 31;
    #pragma unroll
    for (int it = 0; it < 4; ++it) {
        int r = r0 + tr + it * 8, c = c0 + tc;
        tile[tr + it * 8][tc] = (r < R && c < Cc) ? h2f(sb[(long)r * Cc + c]) : 0.f;
    }
    __syncthreads();
    #pragma unroll
    for (int it = 0; it < 4; ++it) {
        int c = c0 + tr + it * 8;
        int r = r0 + tc;
        if (c < Cc && r < R) {
            float v = tile[tc][tr + it * 8];
            if (scale) v *= scale[(long)b * sScale + c];
            db[(long)c * R + r] = f2bf(v);
        }
    }
}

// ====== per-position stats from featT rows ================================
__global__ __launch_bounds__(256) void posStatsT(
    const unsigned short* __restrict__ featT, float* __restrict__ fscale,
    int ci, int hw, float sq)
{
    int b = blockIdx.y, p = blockIdx.x;
    const unsigned short* row = featT + ((long)b * hw + p) * ci;
    float s = 0.f, ss = 0.f;
    for (int c = threadIdx.x; c < ci; c += 256) {
        float v = bf2f(row[c]); s += v; ss += v * v;
    }
    __shared__ float rs[256], rss[256];
    int tid = threadIdx.x;
    rs[tid] = s; rss[tid] = ss; __syncthreads();
    for (int st = 128; st > 0; st >>= 1) {
        if (tid < st) { rs[tid] += rs[tid + st]; rss[tid] += rss[tid + st]; }
        __syncthreads();
    }
    if (tid == 0)
        fscale[(long)b * hw + p] = rs[0] / fmaxf(sqrtf(rss[0]), 1e-12f) * sq;
}

// ==== scale[b,p] = fscale[b,p] / max(||sem[b,:,p]||,eps)  (sem f16) ========
__global__ void enScale(const unsigned short* __restrict__ sem, float* __restrict__ fscale,
                        int ni, int hw)
{
    int b = blockIdx.y;
    int p = blockIdx.x * 256 + threadIdx.x;
    if (p >= hw) return;
    const unsigned short* sb = sem + (long)b * ni * hw + p;
    float ss = 0.f;
    for (int n = 0; n < ni; ++n) { float v = h2f(sb[(long)n * hw]); ss += v * v; }
    fscale[(long)b * hw + p] = fscale[(long)b * hw + p] / fmaxf(sqrtf(ss), 1e-12f);
}

// ==== softmax over p: buf holds sem f16 in, attn bf16 out (IN PLACE) =======
__global__ __launch_bounds__(256) void softmaxHW(
    unsigned short* buf, const float* __restrict__ scale, int ni, int hw)
{
    int b = blockIdx.y, n = blockIdx.x;
    unsigned short* row = buf + ((long)b * ni + n) * hw;
    const float* sc = scale + (long)b * hw;
    __shared__ float red[256];
    int tid = threadIdx.x;

    float m = -1e30f;
    for (int p = tid; p < hw; p += 256) m = fmaxf(m, h2f(row[p]) * sc[p]);
    red[tid] = m; __syncthreads();
    for (int s = 128; s > 0; s >>= 1) {
        if (tid < s) red[tid] = fmaxf(red[tid], red[tid + s]);
        __syncthreads();
    }
    m = red[0]; __syncthreads();

    float sum = 0.f;
    for (int p = tid; p < hw; p += 256) sum += __expf(h2f(row[p]) * sc[p] - m);
    red[tid] = sum; __syncthreads();
    for (int s = 128; s > 0; s >>= 1) {
        if (tid < s) red[tid] += red[tid + s];
        __syncthreads();
    }
    float inv = 1.0f / red[0];

    for (int p = tid; p < hw; p += 256) {
        float v = __expf(h2f(row[p]) * sc[p] - m) * inv;   // read then write
        row[p] = f2bf(v);
    }
}

// ==== softmax over n: buf f16 in, bf16 out (IN PLACE) ======================
__global__ void softmaxN(unsigned short* buf, int hw, int ni)
{
    int b = blockIdx.y;
    int wav = threadIdx.x >> 6, lane = threadIdx.x & 63;
    int p = blockIdx.x * 4 + wav;
    if (p >= hw) return;
    unsigned short* row = buf + ((long)b * hw + p) * ni;
    float m = -1e30f;
    for (int n = lane; n < ni; n += 64) m = fmaxf(m, h2f(row[n]));
    for (int off = 32; off > 0; off >>= 1) m = fmaxf(m, __shfl_xor(m, off));
    float s = 0.f;
    for (int n = lane; n < ni; n += 64) s += __expf(h2f(row[n]) - m);
    for (int off = 32; off > 0; off >>= 1) s += __shfl_xor(s, off);
    float inv = 1.f / s;
    for (int n = lane; n < ni; n += 64) {
        float v = __expf(h2f(row[n]) - m) * inv;
        row[n] = f2bf(v);
    }
}

// ==== lcr[b,col] = 1/max(||g2[b,:,col]||,eps) ==============================
__global__ void lcRnorm(const float* __restrict__ g2, float* __restrict__ lcr)
{
    int b = blockIdx.y;
    int col = blockIdx.x * 256 + threadIdx.x;
    if (col >= GG) return;
    const float* gb = g2 + (long)b * CC * GG + col;
    float ss = 0.f;
    for (int o = 0; o < CC; ++o) { float v = gb[o * GG]; ss += v * v; }
    lcr[b * GG + col] = 1.f / fmaxf(sqrtf(ss), 1e-12f);
}

// ==== lcnT[b,n,o] (normalized) + lcB[b,o,n] (raw), both bf16 ===============
__global__ void buildLc(const float* __restrict__ g2, const float* __restrict__ lcr,
                        unsigned short* __restrict__ lcnT, unsigned short* __restrict__ lcB,
                        int ni, int ptr)
{
    long t = (long)blockIdx.x * 256 + threadIdx.x;
    if (t >= (long)BB * ni * CC) return;
    int o = (int)(t & (CC - 1));
    long r = t >> 8;
    int n = (int)(r % ni);
    int b = (int)(r / ni);
    float raw = g2[(long)b * CC * GG + (long)o * GG + ptr + n];
    lcnT[t] = f2bf(raw * lcr[b * GG + ptr + n]);
    lcB[((long)b * CC + o) * ni + n] = f2bf(raw);
}

// ==== per-position 1/||q[:,p]|| (q f16, CC rows) ===========================
__global__ void qNormCol(const unsigned short* __restrict__ q, float* __restrict__ scl, int hw)
{
    int b = blockIdx.y;
    int p = blockIdx.x * 256 + threadIdx.x;
    if (p >= hw) return;
    const unsigned short* qb = q + (long)b * CC * hw + p;
    float ss = 0.f;
    for (int o = 0; o < CC; ++o) { float v = h2f(qb[(long)o * hw]); ss += v * v; }
    scl[(long)b * hw + p] = 1.f / fmaxf(sqrtf(ss), 1e-12f);
}

// ==== fused weight conversion (all 20 matrices, one launch) ================
struct CvtJob { const float* src; long off; int n; int pad; };
struct CvtJobs { CvtJob j[20]; };
__global__ void cvtAllK(CvtJobs jobs, unsigned short* __restrict__ dst)
{
    const CvtJob J = jobs.j[blockIdx.y];
    int t = blockIdx.x * 256 + threadIdx.x;
    if (t < J.n) dst[J.off + t] = f2bf(J.src[t]);
}

// ==== split-K tail convert: fp32 -> f16/bf16 ===============================
__global__ void cvtOut(const float* __restrict__ src, unsigned short* __restrict__ dst,
                       int n, int toF16)
{
    int i = blockIdx.x * 256 + threadIdx.x;
    if (i >= n) return;
    float v = src[i];
    dst[i] = toF16 ? f2h(v) : f2bf(v);
}

// ===========================================================================
extern "C" void kernel_launch(void* const* d_in, const int* in_sizes, int n_in,
                              void* d_out, int out_size, void* d_ws, size_t ws_size,
                              hipStream_t stream)
{
    (void)n_in; (void)out_size;
    static const int  CI[4]  = {256, 512, 1024, 2048};
    static const int  NI[4]  = {256, 192, 128, 64};
    static const int  HWs[4] = {10000, 2500, 625, 169};
    static const int  PTR[4] = {0, 256, 448, 576};
    static const long OUTOFF[4] = {0, 20480000L, 25600000L, 26880000L};

    const float* feat[4];
    for (int i = 0; i < 4; ++i) feat[i] = (const float*)d_in[i];

    const float *w_sem[4], *w_emb[4], *w_q[4], *w_out[4], *w_res[4];
    bool grouped = (in_sizes[5] == 192 * 512);
    for (int i = 0; i < 4; ++i) {
        if (grouped) {
            w_sem[i] = (const float*)d_in[4 + i];
            w_emb[i] = (const float*)d_in[8 + i];
            w_q[i]   = (const float*)d_in[12 + i];
            w_out[i] = (const float*)d_in[16 + i];
            w_res[i] = (const float*)d_in[20 + i];
        } else {
            int base = 4 + 5 * i;
            w_sem[i] = (const float*)d_in[base + 0];
            w_emb[i] = (const float*)d_in[base + 1];
            w_q[i]   = (const float*)d_in[base + 2];
            w_out[i] = (const float*)d_in[base + 3];
            w_res[i] = (const float*)d_in[base + 4];
        }
    }
    const float* gw1 = (const float*)d_in[24];
    const float* gb1 = (const float*)d_in[25];
    const float* gw2 = (const float*)d_in[26];
    const float* gb2 = (const float*)d_in[27];
    const float* gw3 = (const float*)d_in[28];
    const float* gb3 = (const float*)d_in[29];
    const float* mw1 = (const float*)d_in[30];
    const float* mb1 = (const float*)d_in[31];
    const float* mw2 = (const float*)d_in[32];
    const float* mb2 = (const float*)d_in[33];
    const float* mw3 = (const float*)d_in[34];
    const float* mb3 = (const float*)d_in[35];

    // ---------------- workspace carve-up (~156 MB base) --------------------
    char* wp = (char*)d_ws;
    auto carve = [&](size_t bytes) { char* r = wp; wp += (bytes + 255) & ~(size_t)255; return r; };
    unsigned short* R1 = (unsigned short*)carve(40960000);  // featT L0 bf16
    unsigned short* R2 = (unsigned short*)carve(40960000);  // sem/attn | q/scores/aw
    unsigned short* R3 = (unsigned short*)carve(40960000);  // emb | qnT/wcT
    float* ctxg = (float*)carve(5242880);
    float* gbuf = (float*)carve(5242880);
    float* g2   = (float*)carve(5242880);
    float* h1   = (float*)carve(1310720);
    float* h2   = (float*)carve(1310720);
    unsigned short* lcnT = (unsigned short*)carve(1048576);
    unsigned short* lcB  = (unsigned short*)carve(1048576);
    float* lcr  = (float*)carve(20480);
    float* scl  = (float*)carve(320000);
    float* SK   = (float*)carve(5120000);                   // split-K scratch
    unsigned short* wbuf = (unsigned short*)carve(7275520); // all weights bf16

    // Optional: persist featT for levels 1-3 across phases (skips 4 transCvtF
    // re-runs in phase 2).  Only if the workspace is big enough; falls back to
    // the proven 156 MB layout otherwise.
    unsigned short* featP[4];
    featP[0] = R1;
    {
        size_t f1 = 2UL * BB * 2500 * 512;
        size_t f2 = 2UL * BB * 625 * 1024;
        size_t f3 = 2UL * BB * 169 * 2048;
        size_t used = (size_t)(wp - (char*)d_ws);
        bool persist = (used + f1 + f2 + f3 + (1u << 20) + 4096) <= ws_size;
        if (persist) {
            featP[1] = (unsigned short*)carve(f1);
            featP[2] = (unsigned short*)carve(f2);
            featP[3] = (unsigned short*)carve(f3);
            carve(1u << 20);   // over-read guard for direct-to-LDS staging
        } else {
            featP[1] = featP[2] = featP[3] = R1;
        }
    }
    bool persist = (featP[1] != R1);

    float* outp = (float*)d_out;

    // ---------------- fused weight conversion ------------------------------
    // Order per level: sem, emb, q, res, out  ->  [sem;emb] and [q;res] are
    // contiguous stacked matrices (same K=ci) for the fused projections.
    CvtJobs jobs;
    unsigned short *wsemB[4], *wembB[4], *wqB[4], *woutB[4], *wresB[4];
    long woff = 0; int maxn = 0, jx = 0;
    auto addJob = [&](const float* s, int n, unsigned short** outp_) {
        jobs.j[jx].src = s; jobs.j[jx].off = woff; jobs.j[jx].n = n; jobs.j[jx].pad = 0;
        *outp_ = wbuf + woff;
        woff += (n + 7) & ~7;
        if (n > maxn) maxn = n;
        ++jx;
    };
    for (int i = 0; i < 4; ++i) {
        addJob(w_sem[i], NI[i] * CI[i], &wsemB[i]);
        addJob(w_emb[i], CC * CI[i],    &wembB[i]);
        addJob(w_q[i],   CC * CI[i],    &wqB[i]);
        addJob(w_res[i], CC * CI[i],    &wresB[i]);
        addJob(w_out[i], CC * CC,       &woutB[i]);
    }
    cvtAllK<<<dim3((maxn + 255) / 256, 20), 256, 0, stream>>>(jobs, wbuf);

    auto mgSeg = [&](const unsigned short* A, long sA, int lda,
                     const unsigned short* Bp, long sB, int ldb,
                     void* Cp, long sC, int ldc, long offC,
                     int M, int N, int K, int mode, int kc,
                     void* C2, long sC2, int ldc2, long offC2, int M1, int mode2) {
        if (kc < 1) kc = 1;
        int kLen = ((K + kc - 1) / kc + 31) & ~31;
        int kcc = (K + kLen - 1) / kLen;
        int gxn = (N + 127) / 128, gym = (M + 127) / 128;
        dim3 g((unsigned)(gxn * gym * BB * kcc));
        mfmaGemm<<<g, 256, 0, stream>>>(A, sA, lda, Bp, sB, ldb,
                                        Cp, sC, ldc, offC, M, N, K, kcc, kLen, mode,
                                        gxn, gym, C2, sC2, ldc2, offC2, M1, mode2);
    };
    auto mg = [&](const unsigned short* A, long sA, int lda,
                  const unsigned short* Bp, long sB, int ldb,
                  void* Cp, long sC, int ldc, long offC,
                  int M, int N, int K, int mode, int kc) {
        mgSeg(A, sA, lda, Bp, sB, ldb, Cp, sC, ldc, offC, M, N, K, mode, kc,
              nullptr, 0, 1, 0, M, 0);
    };
    // projection W(M,K)bf16 @ featT(N,K) -> dst contiguous (B,M,N), f16/bf16
    auto projTo = [&](const unsigned short* Wbf, int K, const unsigned short* Xt, long sXt,
                      unsigned short* dst, int M, int N, int fmode) {
        int blocks = ((M + 127) / 128) * ((N + 127) / 128) * BB;
        if (blocks >= 256 || K < 512) {
            mg(Wbf, 0, K, Xt, sXt, K, dst, (long)M * N, N, 0, M, N, K, fmode, 1);
        } else {
            int kc = (256 + blocks - 1) / blocks;
            hipMemsetAsync(SK, 0, (size_t)BB * M * N * 4, stream);
            mg(Wbf, 0, K, Xt, sXt, K, SK, (long)M * N, N, 0, M, N, K, 2, kc);
            long tot = (long)BB * M * N;
            cvtOut<<<dim3((unsigned)((tot + 255) / 256)), 256, 0, stream>>>(
                SK, dst, (int)tot, fmode == 3 ? 1 : 0);
        }
    };

    hipMemsetAsync(ctxg, 0, (size_t)BB * CC * GG * 4, stream);

    // ---------------- Phase 1: per-level attention -> ctxg -----------------
    for (int i = 0; i < 4; ++i) {
        int ci = CI[i], ni = NI[i], hw = HWs[i];
        unsigned short* fT = featP[i];
        transCvtF<<<dim3((hw + 31) / 32, (ci + 31) / 32, BB), 256, 0, stream>>>(
            feat[i], (long)ci * hw, ci, hw, fT, (long)hw * ci, nullptr, 0);
        posStatsT<<<dim3(hw, BB), 256, 0, stream>>>(fT, scl, ci, hw, sqrtf((float)ci));
        if (i < 2) {
            // stacked [sem ; emb]: one featT read -> sem f16 (R2) + emb bf16 (R3)
            mgSeg(wsemB[i], 0, ci, fT, (long)hw * ci, ci,
                  R2, (long)ni * hw, hw, 0,
                  ni + CC, hw, ci, 3, 1,
                  R3, (long)CC * hw, hw, 0, ni, 4);
        } else {
            projTo(wsemB[i], ci, fT, (long)hw * ci, R2, ni, hw, 3);
            projTo(wembB[i], ci, fT, (long)hw * ci, R3, CC, hw, 4);
        }
        enScale<<<dim3((hw + 255) / 256, BB), 256, 0, stream>>>(R2, scl, ni, hw);
        // attn = softmax_p(sem*scl) in place over R2 (bf16 out)
        softmaxHW<<<dim3(ni, BB), 256, 0, stream>>>(R2, scl, ni, hw);
        // ctx += emb @ attn^T -> ctxg (atomic, split-K when skinny)
        {
            int blocks = ((CC + 127) / 128) * ((ni + 127) / 128) * BB;
            int kc = (blocks < 256 && hw >= 512) ? (256 + blocks - 1) / blocks : 1;
            mg(R3, (long)CC * hw, hw, R2, (long)ni * hw, hw,
               ctxg, (long)CC * GG, GG, PTR[i], CC, ni, hw, 2, kc);
        }
    }

    // ---------------- GCN per level (fused across levels) ------------------
    {
        dim3 gl(GG / 64, 1, BB);
        gemmA<<<gl, 256, 0, stream>>>(gw1, 0, ctxg, (long)CC * GG, GG, 0,
                                      h1, (long)64 * GG, GG, 0, gb1,
                                      nullptr, 0, 0, 0, 64, CC, GG, 1, 0,
                                      1, (long)64 * CC, 64);
        gemmA<<<gl, 256, 0, stream>>>(gw2, 0, h1, (long)64 * GG, GG, 0,
                                      h2, (long)64 * GG, GG, 0, gb2,
                                      nullptr, 0, 0, 0, 64, 64, GG, 1, 0,
                                      1, (long)64 * 64, 64);
        dim3 gl2(GG / 64, CC / 64, BB);
        gemmA<<<gl2, 256, 0, stream>>>(gw3, 0, h2, (long)64 * GG, GG, 0,
                                       gbuf, (long)CC * GG, GG, 0, gb3,
                                       ctxg, (long)CC * GG, GG, 0, CC, 64, GG, 0, 0,
                                       1, (long)CC * 64, CC);
    }
    // ---------------- Master GCN + residual -> g2 --------------------------
    {
        dim3 gl(GG / 64, 1, BB);
        gemmA<<<gl, 256, 0, stream>>>(mw1, 0, gbuf, (long)CC * GG, GG, 0,
                                      h1, (long)64 * GG, GG, 0, mb1,
                                      nullptr, 0, 0, 0, 64, CC, GG, 1, 0, 0, 0, 0);
        gemmA<<<gl, 256, 0, stream>>>(mw2, 0, h1, (long)64 * GG, GG, 0,
                                      h2, (long)64 * GG, GG, 0, mb2,
                                      nullptr, 0, 0, 0, 64, 64, GG, 1, 0, 0, 0, 0);
        dim3 gl2(GG / 64, CC / 64, BB);
        gemmA<<<gl2, 256, 0, stream>>>(mw3, 0, h2, (long)64 * GG, GG, 0,
                                       g2, (long)CC * GG, GG, 0, mb3,
                                       gbuf, (long)CC * GG, GG, 0, CC, 64, GG, 0, 0, 0, 0, 0);
    }

    lcRnorm<<<dim3(3, BB), 256, 0, stream>>>(g2, lcr);

    // ---------------- Phase 2: per-level read-out attention ----------------
    for (int i = 0; i < 4; ++i) {
        int ci = CI[i], ni = NI[i], hw = HWs[i];
        long tot = (long)BB * ni * CC;
        buildLc<<<dim3((unsigned)((tot + 255) / 256)), 256, 0, stream>>>(
            g2, lcr, lcnT, lcB, ni, PTR[i]);
        unsigned short* fT = featP[i];
        if (!persist)
            transCvtF<<<dim3((hw + 31) / 32, (ci + 31) / 32, BB), 256, 0, stream>>>(
                feat[i], (long)ci * hw, ci, hw, fT, (long)hw * ci, nullptr, 0);
        if (i < 2) {
            // stacked [q ; res]: one featT read -> q f16 (R2) + res f32 (outp)
            mgSeg(wqB[i], 0, ci, fT, (long)hw * ci, ci,
                  R2, (long)CC * hw, hw, 0,
                  2 * CC, hw, ci, 3, 1,
                  outp, (long)CC * hw, hw, OUTOFF[i], CC, 0);
        } else {
            projTo(wqB[i], ci, fT, (long)hw * ci, R2, CC, hw, 3);
        }
        qNormCol<<<dim3((hw + 255) / 256, BB), 256, 0, stream>>>(R2, scl, hw);
        // qnT = transpose(q)*scl -> R3 bf16 (hw, 256)
        transCvtH<<<dim3((hw + 31) / 32, (CC + 31) / 32, BB), 256, 0, stream>>>(
            R2, (long)CC * hw, CC, hw, R3, (long)hw * CC, scl, hw);
        // scores = qnT @ lcnT^T -> R2 f16 (hw, ni)   (q dead)
        mg(R3, (long)hw * CC, CC, lcnT, (long)ni * CC, CC,
           R2, (long)hw * ni, ni, 0, hw, ni, CC, 3, 1);
        // aw = softmax_n in place over R2 (bf16 out)
        softmaxN<<<dim3((hw + 3) / 4, BB), 256, 0, stream>>>(R2, hw, ni);
        // wcT = aw @ lcB^T -> R3 bf16 (hw, 256)   (qnT dead)
        mg(R2, (long)hw * ni, ni, lcB, (long)CC * ni, ni,
           R3, (long)hw * CC, CC, 0, hw, CC, ni, 4, 1);
        // out = w_res @ f  (levels 2-3: split-K atomic into zeroed region)
        if (i >= 2) {
            int blocks = ((CC + 127) / 128) * ((hw + 127) / 128) * BB;
            if (blocks >= 256 || ci < 512) {
                mg(wresB[i], 0, ci, fT, (long)hw * ci, ci,
                   outp, (long)CC * hw, hw, OUTOFF[i], CC, hw, ci, 0, 1);
            } else {
                int kc = (256 + blocks - 1) / blocks;
                hipMemsetAsync(outp + OUTOFF[i], 0, (size_t)BB * CC * hw * 4, stream);
                mg(wresB[i], 0, ci, fT, (long)hw * ci, ci,
                   outp, (long)CC * hw, hw, OUTOFF[i], CC, hw, ci, 2, kc);
            }
        }
        // out += w_out @ wc
        mg(woutB[i], 0, CC, R3, (long)hw * CC, CC,
           outp, (long)CC * hw, hw, OUTOFF[i], CC, hw, CC, 1, 1);
    }
}

// Round 2
// 1984.092 us; speedup vs baseline: 1.1113x; 1.0720x over previous
//
#include <hip/hip_runtime.h>
#include <math.h>

// ---------------------------------------------------------------------------
// MultiLevelGlobalContext — bf16 MFMA + global_load_lds dbuf + LDS XOR-swizzle
// + XCD swizzle + stacked dual-output GEMMs + segmented-K fused output GEMM.
// Levels: ci={256,512,1024,2048}, hw={10000,2500,625,169}, ni={256,192,128,64}
// B=8, C=256, G=640.
// ---------------------------------------------------------------------------

#define BB 8
#define CC 256
#define GG 640

typedef __attribute__((ext_vector_type(8))) short short8;
typedef __attribute__((ext_vector_type(4))) float f32x4;

__device__ __forceinline__ unsigned short f2bf(float f) {
    unsigned int u = __float_as_uint(f);
    u += 0x7fffu + ((u >> 16) & 1u);
    return (unsigned short)(u >> 16);
}
__device__ __forceinline__ float bf2f(unsigned short h) {
    return __uint_as_float(((unsigned int)h) << 16);
}
__device__ __forceinline__ float h2f(unsigned short h) {
    union { unsigned short u; _Float16 x; } cv; cv.u = h; return (float)cv.x;
}
__device__ __forceinline__ unsigned short f2h(float f) {
    union { unsigned short u; _Float16 x; } cv; cv.x = (_Float16)f; return cv.u;
}

// async global -> LDS, 16B per lane (wave-uniform LDS base + lane*16 layout)
__device__ __forceinline__ void glds16(const unsigned short* g, unsigned short* l) {
    __builtin_amdgcn_global_load_lds(
        (const __attribute__((address_space(1))) void*)g,
        (__attribute__((address_space(3))) void*)l, 16, 0, 0);
}

// LDS k-segment swizzle: logical kseg at (row,phys) is phys ^ f(row).
// f(row)=(row>>1)&3 makes the fragment-read slot (4*row + kq^f) mod 8 a
// bijection per 8 rows -> exact 2-way bank aliasing (free on CDNA4).
__device__ __forceinline__ int swz(int row, int seg) { return seg ^ ((row >> 1) & 3); }

// ===================== bf16 MFMA GEMM: C[b] = A(M,K) @ B(N,K)^T =============
// A, B bf16 (ushort), K contiguous.  Direct-to-LDS double buffer, 1 barrier
// per K-step, XOR-swizzled LDS (source-side pre-swizzle keeps dest linear).
// Segmented B: k<Kb reads B1, k>=Kb reads B2 (col k-Kb).
// Segmented C: rows [0,M1) -> C/mode, rows [M1,M) -> C2/mode2.
// modes: 0 store f32, 1 accum f32, 2 atomicAdd f32, 3 store f16, 4 store bf16
__global__ __launch_bounds__(256) void mfmaGemm(
    const unsigned short* __restrict__ A, long sA, int lda,
    const unsigned short* __restrict__ B, long sB, int ldb,
    const unsigned short* __restrict__ B2p, long sB2, int ldb2, int Kb,
    void* __restrict__ C, long sC, int ldc, long offC,
    int M, int N, int K, int kChunks, int kChunkLen, int mode,
    int gxn, int gym,
    void* __restrict__ C2, long sC2, int ldc2, long offC2, int M1, int mode2)
{
    __shared__ __align__(16) unsigned short As[2][128 * 32];
    __shared__ __align__(16) unsigned short Bs[2][128 * 32];

    // ---- XCD-chunked bijective swizzle (each XCD gets a contiguous chunk) --
    const int nb = (int)gridDim.x;
    int orig = (int)blockIdx.x;
    int xcd = orig & 7, idx = orig >> 3;
    int q8 = nb >> 3, r8 = nb & 7;
    int wg = (xcd < r8) ? (xcd * (q8 + 1) + idx)
                        : (r8 * (q8 + 1) + (xcd - r8) * q8 + idx);
    int mb, nbk, z;
    if (N >= M) { mb = wg % gym; int t = wg / gym; nbk = t % gxn; z = t / gxn; }
    else        { nbk = wg % gxn; int t = wg / gxn; mb = t % gym; z = t / gym; }

    const int b = z / kChunks, chunk = z - b * kChunks;
    const int kbeg = chunk * kChunkLen;
    const int kend = min(K, kbeg + kChunkLen);
    const int m0 = mb * 128, n0 = nbk * 128;

    const unsigned short* Ab  = A + (long)b * sA;
    const unsigned short* Bb  = B + (long)b * sB;
    const unsigned short* Bb2 = B2p ? (B2p + (long)b * sB2) : nullptr;

    const int tid = threadIdx.x;
    const int row = tid >> 2, seg = tid & 3;      // staging: row 0..63, 8-elem seg
    const int wave = tid >> 6, lane = tid & 63;
    const int wm = (wave & 1) * 64, wn = (wave >> 1) * 64;
    const int lm = lane & 15, kq = lane >> 4;

    const bool okA  = ((lda  & 7) == 0) && ((((size_t)Ab)  & 15) == 0);
    const bool okB  = ((ldb  & 7) == 0) && ((((size_t)Bb)  & 15) == 0);
    const bool okB2 = Bb2 && ((ldb2 & 7) == 0) && ((((size_t)Bb2) & 15) == 0);

    f32x4 acc[4][4];
    #pragma unroll
    for (int i = 0; i < 4; ++i)
        #pragma unroll
        for (int j = 0; j < 4; ++j) acc[i][j] = (f32x4){0.f, 0.f, 0.f, 0.f};

    // fast: direct global->LDS; per-lane source col pre-swizzled, dest linear
    auto stageF = [&](const unsigned short* Pb, int ld, int o0,
                      unsigned short* LS, int kg) {
        #pragma unroll
        for (int l = 0; l < 2; ++l) {
            int rf = l * 64 + row;
            const unsigned short* src = Pb + (long)(o0 + rf) * ld + kg + swz(rf, seg) * 8;
            glds16(src, &LS[rf * 32 + seg * 8]);
        }
    };
    // slow: reg roundtrip with zero-fill (unaligned ld / k-tail / row OOB)
    auto stageS = [&](const unsigned short* Pb, int ld, int lim, int o0,
                      unsigned short* LS, int kg, int lend) {
        #pragma unroll
        for (int l = 0; l < 2; ++l) {
            int rf = l * 64 + row;
            int kgg = kg + swz(rf, seg) * 8;
            int krem = lend - kgg;
            int g = o0 + rf;
            uint4 v = make_uint4(0u, 0u, 0u, 0u);
            if (g < lim && krem > 0) {
                const unsigned short* src = Pb + (long)g * ld + kgg;
                if (krem >= 8 && ((((size_t)src) & 15) == 0)) {
                    v = *(const uint4*)src;
                } else {
                    __align__(16) unsigned short tmp[8] = {0,0,0,0,0,0,0,0};
                    int c = krem < 8 ? krem : 8;
                    for (int j = 0; j < c; ++j) tmp[j] = src[j];
                    v = *(const uint4*)tmp;
                }
            }
            *(uint4*)&LS[rf * 32 + seg * 8] = v;
        }
    };
    auto stage = [&](int kg, int buf) {
        bool full = (kg + 32 <= kend);
        if (okA && full) stageF(Ab, lda, m0, As[buf], kg);
        else             stageS(Ab, lda, M, m0, As[buf], kg, kend);
        if (kg < Kb) {
            if (okB && full) stageF(Bb, ldb, n0, Bs[buf], kg);
            else             stageS(Bb, ldb, N, n0, Bs[buf], kg, min(kend, Kb));
        } else {
            int kl = kg - Kb;
            if (okB2 && full) stageF(Bb2, ldb2, n0, Bs[buf], kl);
            else              stageS(Bb2, ldb2, N, n0, Bs[buf], kl, kend - Kb);
        }
    };

    stage(kbeg, 0);
    int cur = 0;
    for (int k0 = kbeg; k0 < kend; k0 += 32) {
        __syncthreads();                       // drains own vmcnt/lgkmcnt -> buf[cur] ready
        if (k0 + 32 < kend) stage(k0 + 32, cur ^ 1);   // prefetch in flight during MFMA

        short8 af[4], bfr[4];
        #pragma unroll
        for (int mt = 0; mt < 4; ++mt) {
            int rA = wm + mt * 16 + lm;
            af[mt] = *(const short8*)&As[cur][rA * 32 + swz(rA, kq) * 8];
        }
        #pragma unroll
        for (int nt = 0; nt < 4; ++nt) {
            int rB = wn + nt * 16 + lm;
            bfr[nt] = *(const short8*)&Bs[cur][rB * 32 + swz(rB, kq) * 8];
        }
        #pragma unroll
        for (int mt = 0; mt < 4; ++mt)
            #pragma unroll
            for (int nt = 0; nt < 4; ++nt)
                acc[mt][nt] = __builtin_amdgcn_mfma_f32_16x16x32_bf16(
                    af[mt], bfr[nt], acc[mt][nt], 0, 0, 0);
        cur ^= 1;
    }

    const long cb1 = (long)b * sC + offC;
    const long cb2 = (long)b * sC2 + offC2;
    #pragma unroll
    for (int mt = 0; mt < 4; ++mt) {
        #pragma unroll
        for (int nt = 0; nt < 4; ++nt) {
            int n_g = n0 + wn + nt * 16 + lm;
            if (n_g >= N) continue;
            #pragma unroll
            for (int r = 0; r < 4; ++r) {
                int m_g = m0 + wm + mt * 16 + kq * 4 + r;
                if (m_g >= M) continue;
                float v = acc[mt][nt][r];
                void* Cp; int md; long cix;
                if (m_g < M1) { Cp = C;  md = mode;  cix = cb1 + (long)m_g * ldc + n_g; }
                else          { Cp = C2; md = mode2; cix = cb2 + (long)(m_g - M1) * ldc2 + n_g; }
                if (md == 0)      ((float*)Cp)[cix] = v;
                else if (md == 1) ((float*)Cp)[cix] += v;
                else if (md == 2) atomicAdd(&((float*)Cp)[cix], v);
                else if (md == 3) ((unsigned short*)Cp)[cix] = f2h(v);
                else              ((unsigned short*)Cp)[cix] = f2bf(v);
            }
        }
    }
}

// ================= fp32 GEMM (GCN layers), with optional per-level fusing ==
__global__ __launch_bounds__(256) void gemmA(
    const float* __restrict__ W, long sW,
    const float* __restrict__ X, long sX, int ldx, long offX,
    float* __restrict__ Cd, long sC, int ldc, long offC,
    const float* __restrict__ bias,
    const float* __restrict__ res, long sR, int ldr, long offR,
    int O, int K, int P, int relu, int accum,
    int lvlFuse, long wStride, int bStride)
{
    __shared__ float Ws[16][64];
    __shared__ float Xs[16][64];
    const int tid = threadIdx.x;
    const int tx = tid & 15;
    const int ty = tid >> 4;
    const int b  = blockIdx.z;
    const int o0 = blockIdx.y * 64;
    const int p0 = blockIdx.x * 64;

    const float* Wp = W;
    const float* bp = bias;
    if (lvlFuse) {
        int lvl = p0 >= 576 ? 3 : p0 >= 448 ? 2 : p0 >= 256 ? 1 : 0;
        Wp += (long)lvl * wStride;
        if (bias) bp += (long)lvl * bStride;
    }
    const float* Wb = Wp + (long)b * sW;
    const float* Xb = X + (long)b * sX + offX;

    float acc[4][4] = {};

    const int wo = tid >> 2;
    const int wk = (tid & 3) * 4;
    const int xp = tid & 63;
    const int xq = tid >> 6;

    for (int k0 = 0; k0 < K; k0 += 16) {
        #pragma unroll
        for (int u = 0; u < 4; ++u) {
            int kk = wk + u;
            float v = 0.f;
            if (o0 + wo < O && k0 + kk < K) v = Wb[(long)(o0 + wo) * K + k0 + kk];
            Ws[kk][wo] = v;
        }
        #pragma unroll
        for (int u = 0; u < 4; ++u) {
            int kk = xq * 4 + u;
            float v = 0.f;
            if (p0 + xp < P && k0 + kk < K) v = Xb[(long)(k0 + kk) * ldx + (p0 + xp)];
            Xs[kk][xp] = v;
        }
        __syncthreads();
        #pragma unroll
        for (int kk = 0; kk < 16; ++kk) {
            float4 wv = *(const float4*)&Ws[kk][ty * 4];
            float4 xv = *(const float4*)&Xs[kk][tx * 4];
            float wa[4] = {wv.x, wv.y, wv.z, wv.w};
            float xa[4] = {xv.x, xv.y, xv.z, xv.w};
            #pragma unroll
            for (int i = 0; i < 4; ++i)
                #pragma unroll
                for (int j = 0; j < 4; ++j)
                    acc[i][j] += wa[i] * xa[j];
        }
        __syncthreads();
    }

    #pragma unroll
    for (int i = 0; i < 4; ++i) {
        int o = o0 + ty * 4 + i;
        if (o >= O) continue;
        #pragma unroll
        for (int j = 0; j < 4; ++j) {
            int p = p0 + tx * 4 + j;
            if (p >= P) continue;
            float v = acc[i][j];
            if (bias) v += bp[o];
            if (relu) v = fmaxf(v, 0.f);
            if (res)  v += res[(long)b * sR + offR + (long)o * ldr + p];
            long ci_ = (long)b * sC + offC + (long)o * ldc + p;
            if (accum) Cd[ci_] += v; else Cd[ci_] = v;
        }
    }
}

// =================== transpose+convert: dst[c][r] = src[r][c]*scale[c] =====
__global__ __launch_bounds__(256) void transCvtF(
    const float* __restrict__ src, long sS, int R, int Cc,
    unsigned short* __restrict__ dst, long sD,
    const float* __restrict__ scale, long sScale)
{
    __shared__ float tile[32][33];
    int b = blockIdx.z;
    int r0 = blockIdx.y * 32, c0 = blockIdx.x * 32;
    const float* sb = src + (long)b * sS;
    unsigned short* db = dst + (long)b * sD;
    int tr = threadIdx.x >> 5, tc = threadIdx.x & 31;
    #pragma unroll
    for (int it = 0; it < 4; ++it) {
        int r = r0 + tr + it * 8, c = c0 + tc;
        tile[tr + it * 8][tc] = (r < R && c < Cc) ? sb[(long)r * Cc + c] : 0.f;
    }
    __syncthreads();
    #pragma unroll
    for (int it = 0; it < 4; ++it) {
        int c = c0 + tr + it * 8;
        int r = r0 + tc;
        if (c < Cc && r < R) {
            float v = tile[tc][tr + it * 8];
            if (scale) v *= scale[(long)b * sScale + c];
            db[(long)c * R + r] = f2bf(v);
        }
    }
}

__global__ __launch_bounds__(256) void transCvtH(
    const unsigned short* __restrict__ src, long sS, int R, int Cc,
    unsigned short* __restrict__ dst, long sD,
    const float* __restrict__ scale, long sScale)
{
    __shared__ float tile[32][33];
    int b = blockIdx.z;
    int r0 = blockIdx.y * 32, c0 = blockIdx.x * 32;
    const unsigned short* sb = src + (long)b * sS;
    unsigned short* db = dst + (long)b * sD;
    int tr = threadIdx.x >> 5, tc = threadIdx.x & 31;
    #pragma unroll
    for (int it = 0; it < 4; ++it) {
        int r = r0 + tr + it * 8, c = c0 + tc;
        tile[tr + it * 8][tc] = (r < R && c < Cc) ? h2f(sb[(long)r * Cc + c]) : 0.f;
    }
    __syncthreads();
    #pragma unroll
    for (int it = 0; it < 4; ++it) {
        int c = c0 + tr + it * 8;
        int r = r0 + tc;
        if (c < Cc && r < R) {
            float v = tile[tc][tr + it * 8];
            if (scale) v *= scale[(long)b * sScale + c];
            db[(long)c * R + r] = f2bf(v);
        }
    }
}

// ====== per-position stats from featT rows ================================
__global__ __launch_bounds__(256) void posStatsT(
    const unsigned short* __restrict__ featT, float* __restrict__ fscale,
    int ci, int hw, float sq)
{
    int b = blockIdx.y, p = blockIdx.x;
    const unsigned short* row = featT + ((long)b * hw + p) * ci;
    float s = 0.f, ss = 0.f;
    for (int c = threadIdx.x; c < ci; c += 256) {
        float v = bf2f(row[c]); s += v; ss += v * v;
    }
    __shared__ float rs[256], rss[256];
    int tid = threadIdx.x;
    rs[tid] = s; rss[tid] = ss; __syncthreads();
    for (int st = 128; st > 0; st >>= 1) {
        if (tid < st) { rs[tid] += rs[tid + st]; rss[tid] += rss[tid + st]; }
        __syncthreads();
    }
    if (tid == 0)
        fscale[(long)b * hw + p] = rs[0] / fmaxf(sqrtf(rss[0]), 1e-12f) * sq;
}

// ==== scale[b,p] = fscale[b,p] / max(||sem[b,:,p]||,eps)  (sem f16) ========
__global__ void enScale(const unsigned short* __restrict__ sem, float* __restrict__ fscale,
                        int ni, int hw)
{
    int b = blockIdx.y;
    int p = blockIdx.x * 256 + threadIdx.x;
    if (p >= hw) return;
    const unsigned short* sb = sem + (long)b * ni * hw + p;
    float ss = 0.f;
    for (int n = 0; n < ni; ++n) { float v = h2f(sb[(long)n * hw]); ss += v * v; }
    fscale[(long)b * hw + p] = fscale[(long)b * hw + p] / fmaxf(sqrtf(ss), 1e-12f);
}

// ==== softmax over p: buf holds sem f16 in, attn bf16 out (IN PLACE) =======
__global__ __launch_bounds__(256) void softmaxHW(
    unsigned short* buf, const float* __restrict__ scale, int ni, int hw)
{
    int b = blockIdx.y, n = blockIdx.x;
    unsigned short* row = buf + ((long)b * ni + n) * hw;
    const float* sc = scale + (long)b * hw;
    __shared__ float red[256];
    int tid = threadIdx.x;

    float m = -1e30f;
    for (int p = tid; p < hw; p += 256) m = fmaxf(m, h2f(row[p]) * sc[p]);
    red[tid] = m; __syncthreads();
    for (int s = 128; s > 0; s >>= 1) {
        if (tid < s) red[tid] = fmaxf(red[tid], red[tid + s]);
        __syncthreads();
    }
    m = red[0]; __syncthreads();

    float sum = 0.f;
    for (int p = tid; p < hw; p += 256) sum += __expf(h2f(row[p]) * sc[p] - m);
    red[tid] = sum; __syncthreads();
    for (int s = 128; s > 0; s >>= 1) {
        if (tid < s) red[tid] += red[tid + s];
        __syncthreads();
    }
    float inv = 1.0f / red[0];

    for (int p = tid; p < hw; p += 256) {
        float v = __expf(h2f(row[p]) * sc[p] - m) * inv;   // read then write
        row[p] = f2bf(v);
    }
}

// ==== softmax over n: buf f16 in, bf16 out (IN PLACE) ======================
__global__ void softmaxN(unsigned short* buf, int hw, int ni)
{
    int b = blockIdx.y;
    int wav = threadIdx.x >> 6, lane = threadIdx.x & 63;
    int p = blockIdx.x * 4 + wav;
    if (p >= hw) return;
    unsigned short* row = buf + ((long)b * hw + p) * ni;
    float m = -1e30f;
    for (int n = lane; n < ni; n += 64) m = fmaxf(m, h2f(row[n]));
    for (int off = 32; off > 0; off >>= 1) m = fmaxf(m, __shfl_xor(m, off));
    float s = 0.f;
    for (int n = lane; n < ni; n += 64) s += __expf(h2f(row[n]) - m);
    for (int off = 32; off > 0; off >>= 1) s += __shfl_xor(s, off);
    float inv = 1.f / s;
    for (int n = lane; n < ni; n += 64) {
        float v = __expf(h2f(row[n]) - m) * inv;
        row[n] = f2bf(v);
    }
}

// ==== lcr[b,col] = 1/max(||g2[b,:,col]||,eps) ==============================
__global__ void lcRnorm(const float* __restrict__ g2, float* __restrict__ lcr)
{
    int b = blockIdx.y;
    int col = blockIdx.x * 256 + threadIdx.x;
    if (col >= GG) return;
    const float* gb = g2 + (long)b * CC * GG + col;
    float ss = 0.f;
    for (int o = 0; o < CC; ++o) { float v = gb[o * GG]; ss += v * v; }
    lcr[b * GG + col] = 1.f / fmaxf(sqrtf(ss), 1e-12f);
}

// ==== lcnT[b,n,o] (normalized) + lcB[b,o,n] (raw), both bf16 ===============
__global__ void buildLc(const float* __restrict__ g2, const float* __restrict__ lcr,
                        unsigned short* __restrict__ lcnT, unsigned short* __restrict__ lcB,
                        int ni, int ptr)
{
    long t = (long)blockIdx.x * 256 + threadIdx.x;
    if (t >= (long)BB * ni * CC) return;
    int o = (int)(t & (CC - 1));
    long r = t >> 8;
    int n = (int)(r % ni);
    int b = (int)(r / ni);
    float raw = g2[(long)b * CC * GG + (long)o * GG + ptr + n];
    lcnT[t] = f2bf(raw * lcr[b * GG + ptr + n]);
    lcB[((long)b * CC + o) * ni + n] = f2bf(raw);
}

// ==== per-position 1/||q[:,p]|| (q f16, CC rows) ===========================
__global__ void qNormCol(const unsigned short* __restrict__ q, float* __restrict__ scl, int hw)
{
    int b = blockIdx.y;
    int p = blockIdx.x * 256 + threadIdx.x;
    if (p >= hw) return;
    const unsigned short* qb = q + (long)b * CC * hw + p;
    float ss = 0.f;
    for (int o = 0; o < CC; ++o) { float v = h2f(qb[(long)o * hw]); ss += v * v; }
    scl[(long)b * hw + p] = 1.f / fmaxf(sqrtf(ss), 1e-12f);
}

// ==== fused weight conversion (20 jobs, strided dest for interleaving) =====
struct CvtJob { const float* src; long off; int n; int K; int ld; int colOff; };
struct CvtJobs { CvtJob j[20]; };
__global__ void cvtAllK(CvtJobs jobs, unsigned short* __restrict__ dst)
{
    const CvtJob J = jobs.j[blockIdx.y];
    int t = blockIdx.x * 256 + threadIdx.x;
    if (t < J.n) {
        int r = t / J.K, c = t - r * J.K;
        dst[J.off + (long)r * J.ld + J.colOff + c] = f2bf(J.src[t]);
    }
}

// ==== split-K tail convert: fp32 -> f16/bf16 ===============================
__global__ void cvtOut(const float* __restrict__ src, unsigned short* __restrict__ dst,
                       int n, int toF16)
{
    int i = blockIdx.x * 256 + threadIdx.x;
    if (i >= n) return;
    float v = src[i];
    dst[i] = toF16 ? f2h(v) : f2bf(v);
}

// ===========================================================================
extern "C" void kernel_launch(void* const* d_in, const int* in_sizes, int n_in,
                              void* d_out, int out_size, void* d_ws, size_t ws_size,
                              hipStream_t stream)
{
    (void)n_in; (void)out_size;
    static const int  CI[4]  = {256, 512, 1024, 2048};
    static const int  NI[4]  = {256, 192, 128, 64};
    static const int  HWs[4] = {10000, 2500, 625, 169};
    static const int  PTR[4] = {0, 256, 448, 576};
    static const long OUTOFF[4] = {0, 20480000L, 25600000L, 26880000L};

    const float* feat[4];
    for (int i = 0; i < 4; ++i) feat[i] = (const float*)d_in[i];

    const float *w_sem[4], *w_emb[4], *w_q[4], *w_out[4], *w_res[4];
    bool grouped = (in_sizes[5] == 192 * 512);
    for (int i = 0; i < 4; ++i) {
        if (grouped) {
            w_sem[i] = (const float*)d_in[4 + i];
            w_emb[i] = (const float*)d_in[8 + i];
            w_q[i]   = (const float*)d_in[12 + i];
            w_out[i] = (const float*)d_in[16 + i];
            w_res[i] = (const float*)d_in[20 + i];
        } else {
            int base = 4 + 5 * i;
            w_sem[i] = (const float*)d_in[base + 0];
            w_emb[i] = (const float*)d_in[base + 1];
            w_q[i]   = (const float*)d_in[base + 2];
            w_out[i] = (const float*)d_in[base + 3];
            w_res[i] = (const float*)d_in[base + 4];
        }
    }
    const float* gw1 = (const float*)d_in[24];
    const float* gb1 = (const float*)d_in[25];
    const float* gw2 = (const float*)d_in[26];
    const float* gb2 = (const float*)d_in[27];
    const float* gw3 = (const float*)d_in[28];
    const float* gb3 = (const float*)d_in[29];
    const float* mw1 = (const float*)d_in[30];
    const float* mb1 = (const float*)d_in[31];
    const float* mw2 = (const float*)d_in[32];
    const float* mb2 = (const float*)d_in[33];
    const float* mw3 = (const float*)d_in[34];
    const float* mb3 = (const float*)d_in[35];

    // ---------------- workspace carve-up (~156 MB base) --------------------
    char* wp = (char*)d_ws;
    auto carve = [&](size_t bytes) { char* r = wp; wp += (bytes + 255) & ~(size_t)255; return r; };
    unsigned short* R1 = (unsigned short*)carve(40960000);  // featT L0 bf16
    unsigned short* R2 = (unsigned short*)carve(40960000);  // sem/attn | q/scores/aw
    unsigned short* R3 = (unsigned short*)carve(40960000);  // emb | qnT/wcT
    float* ctxg = (float*)carve(5242880);
    float* gbuf = (float*)carve(5242880);
    float* g2   = (float*)carve(5242880);
    float* h1   = (float*)carve(1310720);
    float* h2   = (float*)carve(1310720);
    unsigned short* lcnT = (unsigned short*)carve(1048576);
    unsigned short* lcB  = (unsigned short*)carve(1048576);
    float* lcr  = (float*)carve(20480);
    float* scl  = (float*)carve(320000);
    float* SK   = (float*)carve(5120000);                   // split-K scratch
    unsigned short* wbuf = (unsigned short*)carve(7500000); // all weights bf16

    // Optional: persist featT for levels 1-3 across phases (skips transCvtF
    // re-runs in phase 2).  Falls back to the shared-R1 layout otherwise.
    unsigned short* featP[4];
    featP[0] = R1;
    {
        size_t f1 = 2UL * BB * 2500 * 512;
        size_t f2 = 2UL * BB * 625 * 1024;
        size_t f3 = 2UL * BB * 169 * 2048;
        size_t used = (size_t)(wp - (char*)d_ws);
        bool ok = (used + f1 + f2 + f3 + (1u << 20) + 4096) <= ws_size;
        if (ok) {
            featP[1] = (unsigned short*)carve(f1);
            featP[2] = (unsigned short*)carve(f2);
            featP[3] = (unsigned short*)carve(f3);
            carve(1u << 20);   // over-read guard for direct-to-LDS staging
        } else {
            featP[1] = featP[2] = featP[3] = R1;
        }
    }
    bool persist = (featP[1] != R1);

    float* outp = (float*)d_out;

    // ---------------- fused weight conversion ------------------------------
    // Per level: sem, emb (contiguous -> stacked [sem;emb]), q, then
    // interleaved [w_out | w_res] rows of length CC+ci for the fused out GEMM.
    CvtJobs jobs;
    unsigned short *wsemB[4], *wqB[4], *woutresB[4];
    long woff = 0; int maxn = 0, jx = 0;
    auto addJob = [&](const float* s, int n, int K, int ld, int colOff, long off) {
        jobs.j[jx].src = s; jobs.j[jx].off = off; jobs.j[jx].n = n;
        jobs.j[jx].K = K; jobs.j[jx].ld = ld; jobs.j[jx].colOff = colOff;
        if (n > maxn) maxn = n;
        ++jx;
    };
    for (int i = 0; i < 4; ++i) {
        int ci = CI[i], ni = NI[i];
        wsemB[i] = wbuf + woff;
        addJob(w_sem[i], ni * ci, ci, ci, 0, woff);  woff += ni * ci;
        addJob(w_emb[i], CC * ci, ci, ci, 0, woff);  woff += CC * ci;   // stacked after sem
        wqB[i] = wbuf + woff;
        addJob(w_q[i],   CC * ci, ci, ci, 0, woff);  woff += CC * ci;
        woutresB[i] = wbuf + woff;
        addJob(w_out[i], CC * CC, CC, CC + ci, 0,  woff);
        addJob(w_res[i], CC * ci, ci, CC + ci, CC, woff);
        woff += (long)CC * (CC + ci);
    }

    cvtAllK<<<dim3((maxn + 255) / 256, 20), 256, 0, stream>>>(jobs, wbuf);

    auto mgFull = [&](const unsigned short* A, long sA, int lda,
                      const unsigned short* B1, long sB1, int ldb1,
                      const unsigned short* B2, long sB2, int ldb2, int Kb,
                      void* Cp, long sC, int ldc, long offC,
                      int M, int N, int K, int mode, int kc,
                      void* C2, long sC2, int ldc2, long offC2, int M1, int mode2) {
        if (kc < 1) kc = 1;
        int kLen = ((K + kc - 1) / kc + 31) & ~31;
        int kcc = (K + kLen - 1) / kLen;
        int gxn = (N + 127) / 128, gym = (M + 127) / 128;
        dim3 g((unsigned)(gxn * gym * BB * kcc));
        mfmaGemm<<<g, 256, 0, stream>>>(A, sA, lda, B1, sB1, ldb1,
                                        B2, sB2, ldb2, Kb,
                                        Cp, sC, ldc, offC, M, N, K, kcc, kLen, mode,
                                        gxn, gym, C2, sC2, ldc2, offC2, M1, mode2);
    };
    auto mg = [&](const unsigned short* A, long sA, int lda,
                  const unsigned short* Bp, long sB, int ldb,
                  void* Cp, long sC, int ldc, long offC,
                  int M, int N, int K, int mode, int kc) {
        mgFull(A, sA, lda, Bp, sB, ldb, nullptr, 0, 8, K,
               Cp, sC, ldc, offC, M, N, K, mode, kc,
               nullptr, 0, 1, 0, M, 0);
    };
    // projection W(M,K)bf16 @ featT(N,K) -> dst contiguous (B,M,N), f16/bf16
    auto projTo = [&](const unsigned short* Wbf, int K, const unsigned short* Xt, long sXt,
                      unsigned short* dst, int M, int N, int fmode) {
        int blocks = ((M + 127) / 128) * ((N + 127) / 128) * BB;
        if (blocks >= 256 || K < 512) {
            mg(Wbf, 0, K, Xt, sXt, K, dst, (long)M * N, N, 0, M, N, K, fmode, 1);
        } else {
            int kc = (256 + blocks - 1) / blocks;
            hipMemsetAsync(SK, 0, (size_t)BB * M * N * 4, stream);
            mg(Wbf, 0, K, Xt, sXt, K, SK, (long)M * N, N, 0, M, N, K, 2, kc);
            long tot = (long)BB * M * N;
            cvtOut<<<dim3((unsigned)((tot + 255) / 256)), 256, 0, stream>>>(
                SK, dst, (int)tot, fmode == 3 ? 1 : 0);
        }
    };

    hipMemsetAsync(ctxg, 0, (size_t)BB * CC * GG * 4, stream);

    // ---------------- Phase 1: per-level attention -> ctxg -----------------
    for (int i = 0; i < 4; ++i) {
        int ci = CI[i], ni = NI[i], hw = HWs[i];
        unsigned short* fT = featP[i];
        transCvtF<<<dim3((hw + 31) / 32, (ci + 31) / 32, BB), 256, 0, stream>>>(
            feat[i], (long)ci * hw, ci, hw, fT, (long)hw * ci, nullptr, 0);
        posStatsT<<<dim3(hw, BB), 256, 0, stream>>>(fT, scl, ci, hw, sqrtf((float)ci));
        if (i < 2) {
            // stacked [sem ; emb]: one featT read -> sem f16 (R2) + emb bf16 (R3)
            mgFull(wsemB[i], 0, ci, fT, (long)hw * ci, ci, nullptr, 0, 8, ci,
                   R2, (long)ni * hw, hw, 0,
                   ni + CC, hw, ci, 3, 1,
                   R3, (long)CC * hw, hw, 0, ni, 4);
        } else {
            projTo(wsemB[i], ci, fT, (long)hw * ci, R2, ni, hw, 3);
            projTo(wsemB[i] + (long)ni * ci, ci, fT, (long)hw * ci, R3, CC, hw, 4);
        }
        enScale<<<dim3((hw + 255) / 256, BB), 256, 0, stream>>>(R2, scl, ni, hw);
        // attn = softmax_p(sem*scl) in place over R2 (bf16 out)
        softmaxHW<<<dim3(ni, BB), 256, 0, stream>>>(R2, scl, ni, hw);
        // ctx += emb @ attn^T -> ctxg (atomic, split-K when skinny)
        {
            int blocks = ((CC + 127) / 128) * ((ni + 127) / 128) * BB;
            int kc = (blocks < 256 && hw >= 512) ? (256 + blocks - 1) / blocks : 1;
            mg(R3, (long)CC * hw, hw, R2, (long)ni * hw, hw,
               ctxg, (long)CC * GG, GG, PTR[i], CC, ni, hw, 2, kc);
        }
    }

    // ---------------- GCN per level (fused across levels) ------------------
    {
        dim3 gl(GG / 64, 1, BB);
        gemmA<<<gl, 256, 0, stream>>>(gw1, 0, ctxg, (long)CC * GG, GG, 0,
                                      h1, (long)64 * GG, GG, 0, gb1,
                                      nullptr, 0, 0, 0, 64, CC, GG, 1, 0,
                                      1, (long)64 * CC, 64);
        gemmA<<<gl, 256, 0, stream>>>(gw2, 0, h1, (long)64 * GG, GG, 0,
                                      h2, (long)64 * GG, GG, 0, gb2,
                                      nullptr, 0, 0, 0, 64, 64, GG, 1, 0,
                                      1, (long)64 * 64, 64);
        dim3 gl2(GG / 64, CC / 64, BB);
        gemmA<<<gl2, 256, 0, stream>>>(gw3, 0, h2, (long)64 * GG, GG, 0,
                                       gbuf, (long)CC * GG, GG, 0, gb3,
                                       ctxg, (long)CC * GG, GG, 0, CC, 64, GG, 0, 0,
                                       1, (long)CC * 64, CC);
    }
    // ---------------- Master GCN + residual -> g2 --------------------------
    {
        dim3 gl(GG / 64, 1, BB);
        gemmA<<<gl, 256, 0, stream>>>(mw1, 0, gbuf, (long)CC * GG, GG, 0,
                                      h1, (long)64 * GG, GG, 0, mb1,
                                      nullptr, 0, 0, 0, 64, CC, GG, 1, 0, 0, 0, 0);
        gemmA<<<gl, 256, 0, stream>>>(mw2, 0, h1, (long)64 * GG, GG, 0,
                                      h2, (long)64 * GG, GG, 0, mb2,
                                      nullptr, 0, 0, 0, 64, 64, GG, 1, 0, 0, 0, 0);
        dim3 gl2(GG / 64, CC / 64, BB);
        gemmA<<<gl2, 256, 0, stream>>>(mw3, 0, h2, (long)64 * GG, GG, 0,
                                       g2, (long)CC * GG, GG, 0, mb3,
                                       gbuf, (long)CC * GG, GG, 0, CC, 64, GG, 0, 0, 0, 0, 0);
    }

    lcRnorm<<<dim3(3, BB), 256, 0, stream>>>(g2, lcr);

    // ---------------- Phase 2: per-level read-out attention ----------------
    for (int i = 0; i < 4; ++i) {
        int ci = CI[i], ni = NI[i], hw = HWs[i];
        long tot = (long)BB * ni * CC;
        buildLc<<<dim3((unsigned)((tot + 255) / 256)), 256, 0, stream>>>(
            g2, lcr, lcnT, lcB, ni, PTR[i]);
        unsigned short* fT = featP[i];
        if (!persist)
            transCvtF<<<dim3((hw + 31) / 32, (ci + 31) / 32, BB), 256, 0, stream>>>(
                feat[i], (long)ci * hw, ci, hw, fT, (long)hw * ci, nullptr, 0);
        // q -> R2 f16
        projTo(wqB[i], ci, fT, (long)hw * ci, R2, CC, hw, 3);
        qNormCol<<<dim3((hw + 255) / 256, BB), 256, 0, stream>>>(R2, scl, hw);
        // qnT = transpose(q)*scl -> R3 bf16 (hw, 256)
        transCvtH<<<dim3((hw + 31) / 32, (CC + 31) / 32, BB), 256, 0, stream>>>(
            R2, (long)CC * hw, CC, hw, R3, (long)hw * CC, scl, hw);
        // scores = qnT @ lcnT^T -> R2 f16 (hw, ni)   (q dead)
        mg(R3, (long)hw * CC, CC, lcnT, (long)ni * CC, CC,
           R2, (long)hw * ni, ni, 0, hw, ni, CC, 3, 1);
        // aw = softmax_n in place over R2 (bf16 out)
        softmaxN<<<dim3((hw + 3) / 4, BB), 256, 0, stream>>>(R2, hw, ni);
        // wcT = aw @ lcB^T -> R3 bf16 (hw, 256)   (qnT dead)
        mg(R2, (long)hw * ni, ni, lcB, (long)CC * ni, ni,
           R3, (long)hw * CC, CC, 0, hw, CC, ni, 4, 1);
        // out = [w_out | w_res] @ [wcT ; featT]  (segmented K, single write)
        {
            int K = CC + ci;
            int blocks = ((CC + 127) / 128) * ((hw + 127) / 128) * BB;
            if (blocks >= 256) {
                mgFull(woutresB[i], 0, K, R3, (long)hw * CC, CC,
                       fT, (long)hw * ci, ci, CC,
                       outp, (long)CC * hw, hw, OUTOFF[i], CC, hw, K, 0, 1,
                       nullptr, 0, 1, 0, CC, 0);
            } else {
                int kc = (256 + blocks - 1) / blocks;
                hipMemsetAsync(outp + OUTOFF[i], 0, (size_t)BB * CC * hw * 4, stream);
                mgFull(woutresB[i], 0, K, R3, (long)hw * CC, CC,
                       fT, (long)hw * ci, ci, CC,
                       outp, (long)CC * hw, hw, OUTOFF[i], CC, hw, K, 2, kc,
                       nullptr, 0, 1, 0, CC, 0);
            }
        }
    }
}

// Round 3
// 1972.692 us; speedup vs baseline: 1.1177x; 1.0058x over previous
//
#include <hip/hip_runtime.h>
#include <math.h>

// ---------------------------------------------------------------------------
// MultiLevelGlobalContext — bf16 MFMA + global_load_lds + counted-vmcnt
// 3-buffer pipeline + LDS XOR-swizzle + XCD swizzle + stacked dual-output
// GEMMs + segmented-K fused output GEMM.
// Levels: ci={256,512,1024,2048}, hw={10000,2500,625,169}, ni={256,192,128,64}
// B=8, C=256, G=640.
// ---------------------------------------------------------------------------

#define BB 8
#define CC 256
#define GG 640

typedef __attribute__((ext_vector_type(8))) short short8;
typedef __attribute__((ext_vector_type(4))) float f32x4;

__device__ __forceinline__ unsigned short f2bf(float f) {
    unsigned int u = __float_as_uint(f);
    u += 0x7fffu + ((u >> 16) & 1u);
    return (unsigned short)(u >> 16);
}
__device__ __forceinline__ float bf2f(unsigned short h) {
    return __uint_as_float(((unsigned int)h) << 16);
}
__device__ __forceinline__ float h2f(unsigned short h) {
    union { unsigned short u; _Float16 x; } cv; cv.u = h; return (float)cv.x;
}
__device__ __forceinline__ unsigned short f2h(float f) {
    union { unsigned short u; _Float16 x; } cv; cv.x = (_Float16)f; return cv.u;
}

// async global -> LDS, 16B per lane (wave-uniform LDS base + lane*16 layout)
__device__ __forceinline__ void glds16(const unsigned short* g, unsigned short* l) {
    __builtin_amdgcn_global_load_lds(
        (const __attribute__((address_space(1))) void*)g,
        (__attribute__((address_space(3))) void*)l, 16, 0, 0);
}

// LDS k-segment swizzle: logical kseg at (row,phys) is phys ^ f(row).
// f(row)=(row>>1)&3 makes the fragment-read slot (4*row + kq^f) mod 8 a
// bijection per 8 rows -> exact 2-way bank aliasing (free on CDNA4).
__device__ __forceinline__ int swz(int row, int seg) { return seg ^ ((row >> 1) & 3); }

// ===================== bf16 MFMA GEMM: C[b] = A(M,K) @ B(N,K)^T =============
// A, B bf16 (ushort), K contiguous.  Direct-to-LDS, 3-buffer depth-2 pipeline
// with counted vmcnt (never drains to 0 in steady state); fallback 2-buffer
// drain loop for unaligned/tail chunks.  XOR-swizzled LDS (source-side
// pre-swizzle keeps dest linear).
// Segmented B: k<Kb reads B1, k>=Kb reads B2 (col k-Kb).
// Segmented C: rows [0,M1) -> C/mode, rows [M1,M) -> C2/mode2.
// modes: 0 store f32, 1 accum f32, 2 atomicAdd f32, 3 store f16, 4 store bf16
__global__ __launch_bounds__(256) void mfmaGemm(
    const unsigned short* __restrict__ A, long sA, int lda,
    const unsigned short* __restrict__ B, long sB, int ldb,
    const unsigned short* __restrict__ B2p, long sB2, int ldb2, int Kb,
    void* __restrict__ C, long sC, int ldc, long offC,
    int M, int N, int K, int kChunks, int kChunkLen, int mode,
    int gxn, int gym,
    void* __restrict__ C2, long sC2, int ldc2, long offC2, int M1, int mode2)
{
    __shared__ __align__(16) unsigned short As[3][128 * 32];
    __shared__ __align__(16) unsigned short Bs[3][128 * 32];

    // ---- XCD-chunked bijective swizzle (each XCD gets a contiguous chunk) --
    const int nb = (int)gridDim.x;
    int orig = (int)blockIdx.x;
    int xcd = orig & 7, idx = orig >> 3;
    int q8 = nb >> 3, r8 = nb & 7;
    int wg = (xcd < r8) ? (xcd * (q8 + 1) + idx)
                        : (r8 * (q8 + 1) + (xcd - r8) * q8 + idx);
    int mb, nbk, z;
    if (N >= M) { mb = wg % gym; int t = wg / gym; nbk = t % gxn; z = t / gxn; }
    else        { nbk = wg % gxn; int t = wg / gxn; mb = t % gym; z = t / gym; }

    const int b = z / kChunks, chunk = z - b * kChunks;
    const int kbeg = chunk * kChunkLen;
    const int kend = min(K, kbeg + kChunkLen);
    const int m0 = mb * 128, n0 = nbk * 128;

    const unsigned short* Ab  = A + (long)b * sA;
    const unsigned short* Bb  = B + (long)b * sB;
    const unsigned short* Bb2 = B2p ? (B2p + (long)b * sB2) : nullptr;

    const int tid = threadIdx.x;
    const int row = tid >> 2, seg = tid & 3;      // staging: row 0..63, 8-elem seg
    const int wave = tid >> 6, lane = tid & 63;
    const int wm = (wave & 1) * 64, wn = (wave >> 1) * 64;
    const int lm = lane & 15, kq = lane >> 4;

    const bool okA  = ((lda  & 7) == 0) && ((((size_t)Ab)  & 15) == 0);
    const bool okB  = ((ldb  & 7) == 0) && ((((size_t)Bb)  & 15) == 0);
    const bool okB2 = Bb2 && ((ldb2 & 7) == 0) && ((((size_t)Bb2) & 15) == 0);

    f32x4 acc[4][4];
    #pragma unroll
    for (int i = 0; i < 4; ++i)
        #pragma unroll
        for (int j = 0; j < 4; ++j) acc[i][j] = (f32x4){0.f, 0.f, 0.f, 0.f};

    // fast: direct global->LDS; per-lane source col pre-swizzled, dest linear
    auto stageP = [&](int kg, int buf) {
        #pragma unroll
        for (int l = 0; l < 2; ++l) {
            int rf = l * 64 + row;
            const unsigned short* src = Ab + (long)(m0 + rf) * lda + kg + swz(rf, seg) * 8;
            glds16(src, &As[buf][rf * 32 + seg * 8]);
        }
        const unsigned short* Pb; int ld; long kg2;
        if (kg < Kb) { Pb = Bb;  ld = ldb;  kg2 = kg; }
        else         { Pb = Bb2; ld = ldb2; kg2 = kg - Kb; }
        #pragma unroll
        for (int l = 0; l < 2; ++l) {
            int rf = l * 64 + row;
            const unsigned short* src = Pb + (long)(n0 + rf) * ld + kg2 + swz(rf, seg) * 8;
            glds16(src, &Bs[buf][rf * 32 + seg * 8]);
        }
    };
    // slow: reg roundtrip with zero-fill (unaligned ld / k-tail / row OOB)
    auto stageS = [&](const unsigned short* Pb, int ld, int lim, int o0,
                      unsigned short* LS, int kg, int lend) {
        #pragma unroll
        for (int l = 0; l < 2; ++l) {
            int rf = l * 64 + row;
            int kgg = kg + swz(rf, seg) * 8;
            int krem = lend - kgg;
            int g = o0 + rf;
            uint4 v = make_uint4(0u, 0u, 0u, 0u);
            if (g < lim && krem > 0) {
                const unsigned short* src = Pb + (long)g * ld + kgg;
                if (krem >= 8 && ((((size_t)src) & 15) == 0)) {
                    v = *(const uint4*)src;
                } else {
                    __align__(16) unsigned short tmp[8] = {0,0,0,0,0,0,0,0};
                    int c = krem < 8 ? krem : 8;
                    for (int j = 0; j < c; ++j) tmp[j] = src[j];
                    v = *(const uint4*)tmp;
                }
            }
            *(uint4*)&LS[rf * 32 + seg * 8] = v;
        }
    };
    auto stage = [&](int kg, int buf) {
        bool full = (kg + 32 <= kend);
        if (okA && full) {
            #pragma unroll
            for (int l = 0; l < 2; ++l) {
                int rf = l * 64 + row;
                const unsigned short* src = Ab + (long)(m0 + rf) * lda + kg + swz(rf, seg) * 8;
                glds16(src, &As[buf][rf * 32 + seg * 8]);
            }
        } else stageS(Ab, lda, M, m0, As[buf], kg, kend);
        if (kg < Kb) {
            if (okB && full && kg + 32 <= Kb) {
                #pragma unroll
                for (int l = 0; l < 2; ++l) {
                    int rf = l * 64 + row;
                    const unsigned short* src = Bb + (long)(n0 + rf) * ldb + kg + swz(rf, seg) * 8;
                    glds16(src, &Bs[buf][rf * 32 + seg * 8]);
                }
            } else stageS(Bb, ldb, N, n0, Bs[buf], kg, min(kend, Kb));
        } else {
            int kl = kg - Kb;
            if (okB2 && full) {
                #pragma unroll
                for (int l = 0; l < 2; ++l) {
                    int rf = l * 64 + row;
                    const unsigned short* src = Bb2 + (long)(n0 + rf) * ldb2 + kl + swz(rf, seg) * 8;
                    glds16(src, &Bs[buf][rf * 32 + seg * 8]);
                }
            } else stageS(Bb2, ldb2, N, n0, Bs[buf], kl, kend - Kb);
        }
    };

    // fragment read + 16 MFMA from buffer `cur`
    auto compute = [&](int cur) {
        short8 af[4], bfr[4];
        #pragma unroll
        for (int mt = 0; mt < 4; ++mt) {
            int rA = wm + mt * 16 + lm;
            af[mt] = *(const short8*)&As[cur][rA * 32 + swz(rA, kq) * 8];
        }
        #pragma unroll
        for (int nt = 0; nt < 4; ++nt) {
            int rB = wn + nt * 16 + lm;
            bfr[nt] = *(const short8*)&Bs[cur][rB * 32 + swz(rB, kq) * 8];
        }
        #pragma unroll
        for (int mt = 0; mt < 4; ++mt)
            #pragma unroll
            for (int nt = 0; nt < 4; ++nt)
                acc[mt][nt] = __builtin_amdgcn_mfma_f32_16x16x32_bf16(
                    af[mt], bfr[nt], acc[mt][nt], 0, 0, 0);
    };

    // Pipelined path: all-fast staging, K-chunk multiple of 32, segment
    // boundary 32-aligned.  Depth-2 prefetch, counted vmcnt across barriers.
    const bool pipe = okA && okB && (B2p == nullptr || okB2) &&
                      (((kend - kbeg) & 31) == 0) && ((Kb & 31) == 0);

    if (pipe) {
        stageP(kbeg, 0);                              // vm in-flight: 4
        if (kbeg + 32 < kend) stageP(kbeg + 32, 1);   // vm in-flight: 8
        int cur = 0;
        for (int k0 = kbeg; k0 < kend; k0 += 32) {
            // own step-k0 loads complete; next step's may stay in flight
            if (k0 + 32 < kend) asm volatile("s_waitcnt vmcnt(4)" ::: "memory");
            else                asm volatile("s_waitcnt vmcnt(0)" ::: "memory");
            __builtin_amdgcn_s_barrier();             // all waves' k0 loads done
            if (k0 + 64 < kend) {                     // stage k0+64 into cur+2 (mod 3)
                int nb3 = cur + 2; if (nb3 >= 3) nb3 -= 3;
                stageP(k0 + 64, nb3);
            }
            compute(cur);
            cur = (cur + 1 == 3) ? 0 : cur + 1;
        }
    } else {
        stage(kbeg, 0);
        int cur = 0;
        for (int k0 = kbeg; k0 < kend; k0 += 32) {
            __syncthreads();                   // drains own vmcnt/lgkmcnt
            if (k0 + 32 < kend) stage(k0 + 32, cur ^ 1);
            compute(cur);
            cur ^= 1;
        }
    }

    const long cb1 = (long)b * sC + offC;
    const long cb2 = (long)b * sC2 + offC2;
    #pragma unroll
    for (int mt = 0; mt < 4; ++mt) {
        #pragma unroll
        for (int nt = 0; nt < 4; ++nt) {
            int n_g = n0 + wn + nt * 16 + lm;
            if (n_g >= N) continue;
            #pragma unroll
            for (int r = 0; r < 4; ++r) {
                int m_g = m0 + wm + mt * 16 + kq * 4 + r;
                if (m_g >= M) continue;
                float v = acc[mt][nt][r];
                void* Cp; int md; long cix;
                if (m_g < M1) { Cp = C;  md = mode;  cix = cb1 + (long)m_g * ldc + n_g; }
                else          { Cp = C2; md = mode2; cix = cb2 + (long)(m_g - M1) * ldc2 + n_g; }
                if (md == 0)      ((float*)Cp)[cix] = v;
                else if (md == 1) ((float*)Cp)[cix] += v;
                else if (md == 2) atomicAdd(&((float*)Cp)[cix], v);
                else if (md == 3) ((unsigned short*)Cp)[cix] = f2h(v);
                else              ((unsigned short*)Cp)[cix] = f2bf(v);
            }
        }
    }
}

// ================= fp32 GEMM (GCN layers), with optional per-level fusing ==
__global__ __launch_bounds__(256) void gemmA(
    const float* __restrict__ W, long sW,
    const float* __restrict__ X, long sX, int ldx, long offX,
    float* __restrict__ Cd, long sC, int ldc, long offC,
    const float* __restrict__ bias,
    const float* __restrict__ res, long sR, int ldr, long offR,
    int O, int K, int P, int relu, int accum,
    int lvlFuse, long wStride, int bStride)
{
    __shared__ float Ws[16][64];
    __shared__ float Xs[16][64];
    const int tid = threadIdx.x;
    const int tx = tid & 15;
    const int ty = tid >> 4;
    const int b  = blockIdx.z;
    const int o0 = blockIdx.y * 64;
    const int p0 = blockIdx.x * 64;

    const float* Wp = W;
    const float* bp = bias;
    if (lvlFuse) {
        int lvl = p0 >= 576 ? 3 : p0 >= 448 ? 2 : p0 >= 256 ? 1 : 0;
        Wp += (long)lvl * wStride;
        if (bias) bp += (long)lvl * bStride;
    }
    const float* Wb = Wp + (long)b * sW;
    const float* Xb = X + (long)b * sX + offX;

    float acc[4][4] = {};

    const int wo = tid >> 2;
    const int wk = (tid & 3) * 4;
    const int xp = tid & 63;
    const int xq = tid >> 6;

    for (int k0 = 0; k0 < K; k0 += 16) {
        #pragma unroll
        for (int u = 0; u < 4; ++u) {
            int kk = wk + u;
            float v = 0.f;
            if (o0 + wo < O && k0 + kk < K) v = Wb[(long)(o0 + wo) * K + k0 + kk];
            Ws[kk][wo] = v;
        }
        #pragma unroll
        for (int u = 0; u < 4; ++u) {
            int kk = xq * 4 + u;
            float v = 0.f;
            if (p0 + xp < P && k0 + kk < K) v = Xb[(long)(k0 + kk) * ldx + (p0 + xp)];
            Xs[kk][xp] = v;
        }
        __syncthreads();
        #pragma unroll
        for (int kk = 0; kk < 16; ++kk) {
            float4 wv = *(const float4*)&Ws[kk][ty * 4];
            float4 xv = *(const float4*)&Xs[kk][tx * 4];
            float wa[4] = {wv.x, wv.y, wv.z, wv.w};
            float xa[4] = {xv.x, xv.y, xv.z, xv.w};
            #pragma unroll
            for (int i = 0; i < 4; ++i)
                #pragma unroll
                for (int j = 0; j < 4; ++j)
                    acc[i][j] += wa[i] * xa[j];
        }
        __syncthreads();
    }

    #pragma unroll
    for (int i = 0; i < 4; ++i) {
        int o = o0 + ty * 4 + i;
        if (o >= O) continue;
        #pragma unroll
        for (int j = 0; j < 4; ++j) {
            int p = p0 + tx * 4 + j;
            if (p >= P) continue;
            float v = acc[i][j];
            if (bias) v += bp[o];
            if (relu) v = fmaxf(v, 0.f);
            if (res)  v += res[(long)b * sR + offR + (long)o * ldr + p];
            long ci_ = (long)b * sC + offC + (long)o * ldc + p;
            if (accum) Cd[ci_] += v; else Cd[ci_] = v;
        }
    }
}

// =================== transpose+convert: dst[c][r] = src[r][c]*scale[c] =====
__global__ __launch_bounds__(256) void transCvtF(
    const float* __restrict__ src, long sS, int R, int Cc,
    unsigned short* __restrict__ dst, long sD,
    const float* __restrict__ scale, long sScale)
{
    __shared__ float tile[32][33];
    int b = blockIdx.z;
    int r0 = blockIdx.y * 32, c0 = blockIdx.x * 32;
    const float* sb = src + (long)b * sS;
    unsigned short* db = dst + (long)b * sD;
    int tr = threadIdx.x >> 5, tc = threadIdx.x & 31;
    #pragma unroll
    for (int it = 0; it < 4; ++it) {
        int r = r0 + tr + it * 8, c = c0 + tc;
        tile[tr + it * 8][tc] = (r < R && c < Cc) ? sb[(long)r * Cc + c] : 0.f;
    }
    __syncthreads();
    #pragma unroll
    for (int it = 0; it < 4; ++it) {
        int c = c0 + tr + it * 8;
        int r = r0 + tc;
        if (c < Cc && r < R) {
            float v = tile[tc][tr + it * 8];
            if (scale) v *= scale[(long)b * sScale + c];
            db[(long)c * R + r] = f2bf(v);
        }
    }
}

__global__ __launch_bounds__(256) void transCvtH(
    const unsigned short* __restrict__ src, long sS, int R, int Cc,
    unsigned short* __restrict__ dst, long sD,
    const float* __restrict__ scale, long sScale)
{
    __shared__ float tile[32][33];
    int b = blockIdx.z;
    int r0 = blockIdx.y * 32, c0 = blockIdx.x * 32;
    const unsigned short* sb = src + (long)b * sS;
    unsigned short* db = dst + (long)b * sD;
    int tr = threadIdx.x >> 5, tc = threadIdx.x & 31;
    #pragma unroll
    for (int it = 0; it < 4; ++it) {
        int r = r0 + tr + it * 8, c = c0 + tc;
        tile[tr + it * 8][tc] = (r < R && c < Cc) ? h2f(sb[(long)r * Cc + c]) : 0.f;
    }
    __syncthreads();
    #pragma unroll
    for (int it = 0; it < 4; ++it) {
        int c = c0 + tr + it * 8;
        int r = r0 + tc;
        if (c < Cc && r < R) {
            float v = tile[tc][tr + it * 8];
            if (scale) v *= scale[(long)b * sScale + c];
            db[(long)c * R + r] = f2bf(v);
        }
    }
}

// ====== per-position stats from featT rows ================================
__global__ __launch_bounds__(256) void posStatsT(
    const unsigned short* __restrict__ featT, float* __restrict__ fscale,
    int ci, int hw, float sq)
{
    int b = blockIdx.y, p = blockIdx.x;
    const unsigned short* row = featT + ((long)b * hw + p) * ci;
    float s = 0.f, ss = 0.f;
    for (int c = threadIdx.x; c < ci; c += 256) {
        float v = bf2f(row[c]); s += v; ss += v * v;
    }
    __shared__ float rs[256], rss[256];
    int tid = threadIdx.x;
    rs[tid] = s; rss[tid] = ss; __syncthreads();
    for (int st = 128; st > 0; st >>= 1) {
        if (tid < st) { rs[tid] += rs[tid + st]; rss[tid] += rss[tid + st]; }
        __syncthreads();
    }
    if (tid == 0)
        fscale[(long)b * hw + p] = rs[0] / fmaxf(sqrtf(rss[0]), 1e-12f) * sq;
}

// ==== scale[b,p] = fscale[b,p] / max(||sem[b,:,p]||,eps)  (sem f16) ========
__global__ void enScale(const unsigned short* __restrict__ sem, float* __restrict__ fscale,
                        int ni, int hw)
{
    int b = blockIdx.y;
    int p = blockIdx.x * 256 + threadIdx.x;
    if (p >= hw) return;
    const unsigned short* sb = sem + (long)b * ni * hw + p;
    float ss = 0.f;
    for (int n = 0; n < ni; ++n) { float v = h2f(sb[(long)n * hw]); ss += v * v; }
    fscale[(long)b * hw + p] = fscale[(long)b * hw + p] / fmaxf(sqrtf(ss), 1e-12f);
}

// ==== softmax over p: buf holds sem f16 in, attn bf16 out (IN PLACE) =======
__global__ __launch_bounds__(256) void softmaxHW(
    unsigned short* buf, const float* __restrict__ scale, int ni, int hw)
{
    int b = blockIdx.y, n = blockIdx.x;
    unsigned short* row = buf + ((long)b * ni + n) * hw;
    const float* sc = scale + (long)b * hw;
    __shared__ float red[256];
    int tid = threadIdx.x;

    float m = -1e30f;
    for (int p = tid; p < hw; p += 256) m = fmaxf(m, h2f(row[p]) * sc[p]);
    red[tid] = m; __syncthreads();
    for (int s = 128; s > 0; s >>= 1) {
        if (tid < s) red[tid] = fmaxf(red[tid], red[tid + s]);
        __syncthreads();
    }
    m = red[0]; __syncthreads();

    float sum = 0.f;
    for (int p = tid; p < hw; p += 256) sum += __expf(h2f(row[p]) * sc[p] - m);
    red[tid] = sum; __syncthreads();
    for (int s = 128; s > 0; s >>= 1) {
        if (tid < s) red[tid] += red[tid + s];
        __syncthreads();
    }
    float inv = 1.0f / red[0];

    for (int p = tid; p < hw; p += 256) {
        float v = __expf(h2f(row[p]) * sc[p] - m) * inv;   // read then write
        row[p] = f2bf(v);
    }
}

// ==== softmax over n: buf f16 in, bf16 out (IN PLACE) ======================
__global__ void softmaxN(unsigned short* buf, int hw, int ni)
{
    int b = blockIdx.y;
    int wav = threadIdx.x >> 6, lane = threadIdx.x & 63;
    int p = blockIdx.x * 4 + wav;
    if (p >= hw) return;
    unsigned short* row = buf + ((long)b * hw + p) * ni;
    float m = -1e30f;
    for (int n = lane; n < ni; n += 64) m = fmaxf(m, h2f(row[n]));
    for (int off = 32; off > 0; off >>= 1) m = fmaxf(m, __shfl_xor(m, off));
    float s = 0.f;
    for (int n = lane; n < ni; n += 64) s += __expf(h2f(row[n]) - m);
    for (int off = 32; off > 0; off >>= 1) s += __shfl_xor(s, off);
    float inv = 1.f / s;
    for (int n = lane; n < ni; n += 64) {
        float v = __expf(h2f(row[n]) - m) * inv;
        row[n] = f2bf(v);
    }
}

// ==== lcr[b,col] = 1/max(||g2[b,:,col]||,eps) ==============================
__global__ void lcRnorm(const float* __restrict__ g2, float* __restrict__ lcr)
{
    int b = blockIdx.y;
    int col = blockIdx.x * 256 + threadIdx.x;
    if (col >= GG) return;
    const float* gb = g2 + (long)b * CC * GG + col;
    float ss = 0.f;
    for (int o = 0; o < CC; ++o) { float v = gb[o * GG]; ss += v * v; }
    lcr[b * GG + col] = 1.f / fmaxf(sqrtf(ss), 1e-12f);
}

// ==== lcnT[b,n,o] (normalized) + lcB[b,o,n] (raw), both bf16 ===============
__global__ void buildLc(const float* __restrict__ g2, const float* __restrict__ lcr,
                        unsigned short* __restrict__ lcnT, unsigned short* __restrict__ lcB,
                        int ni, int ptr)
{
    long t = (long)blockIdx.x * 256 + threadIdx.x;
    if (t >= (long)BB * ni * CC) return;
    int o = (int)(t & (CC - 1));
    long r = t >> 8;
    int n = (int)(r % ni);
    int b = (int)(r / ni);
    float raw = g2[(long)b * CC * GG + (long)o * GG + ptr + n];
    lcnT[t] = f2bf(raw * lcr[b * GG + ptr + n]);
    lcB[((long)b * CC + o) * ni + n] = f2bf(raw);
}

// ==== per-position 1/||q[:,p]|| (q f16, CC rows) ===========================
__global__ void qNormCol(const unsigned short* __restrict__ q, float* __restrict__ scl, int hw)
{
    int b = blockIdx.y;
    int p = blockIdx.x * 256 + threadIdx.x;
    if (p >= hw) return;
    const unsigned short* qb = q + (long)b * CC * hw + p;
    float ss = 0.f;
    for (int o = 0; o < CC; ++o) { float v = h2f(qb[(long)o * hw]); ss += v * v; }
    scl[(long)b * hw + p] = 1.f / fmaxf(sqrtf(ss), 1e-12f);
}

// ==== fused weight conversion (20 jobs, strided dest for interleaving) =====
struct CvtJob { const float* src; long off; int n; int K; int ld; int colOff; };
struct CvtJobs { CvtJob j[20]; };
__global__ void cvtAllK(CvtJobs jobs, unsigned short* __restrict__ dst)
{
    const CvtJob J = jobs.j[blockIdx.y];
    int t = blockIdx.x * 256 + threadIdx.x;
    if (t < J.n) {
        int r = t / J.K, c = t - r * J.K;
        dst[J.off + (long)r * J.ld + J.colOff + c] = f2bf(J.src[t]);
    }
}

// ==== split-K tail convert: fp32 -> f16/bf16 ===============================
__global__ void cvtOut(const float* __restrict__ src, unsigned short* __restrict__ dst,
                       int n, int toF16)
{
    int i = blockIdx.x * 256 + threadIdx.x;
    if (i >= n) return;
    float v = src[i];
    dst[i] = toF16 ? f2h(v) : f2bf(v);
}

// ===========================================================================
extern "C" void kernel_launch(void* const* d_in, const int* in_sizes, int n_in,
                              void* d_out, int out_size, void* d_ws, size_t ws_size,
                              hipStream_t stream)
{
    (void)n_in; (void)out_size;
    static const int  CI[4]  = {256, 512, 1024, 2048};
    static const int  NI[4]  = {256, 192, 128, 64};
    static const int  HWs[4] = {10000, 2500, 625, 169};
    static const int  PTR[4] = {0, 256, 448, 576};
    static const long OUTOFF[4] = {0, 20480000L, 25600000L, 26880000L};

    const float* feat[4];
    for (int i = 0; i < 4; ++i) feat[i] = (const float*)d_in[i];

    const float *w_sem[4], *w_emb[4], *w_q[4], *w_out[4], *w_res[4];
    bool grouped = (in_sizes[5] == 192 * 512);
    for (int i = 0; i < 4; ++i) {
        if (grouped) {
            w_sem[i] = (const float*)d_in[4 + i];
            w_emb[i] = (const float*)d_in[8 + i];
            w_q[i]   = (const float*)d_in[12 + i];
            w_out[i] = (const float*)d_in[16 + i];
            w_res[i] = (const float*)d_in[20 + i];
        } else {
            int base = 4 + 5 * i;
            w_sem[i] = (const float*)d_in[base + 0];
            w_emb[i] = (const float*)d_in[base + 1];
            w_q[i]   = (const float*)d_in[base + 2];
            w_out[i] = (const float*)d_in[base + 3];
            w_res[i] = (const float*)d_in[base + 4];
        }
    }
    const float* gw1 = (const float*)d_in[24];
    const float* gb1 = (const float*)d_in[25];
    const float* gw2 = (const float*)d_in[26];
    const float* gb2 = (const float*)d_in[27];
    const float* gw3 = (const float*)d_in[28];
    const float* gb3 = (const float*)d_in[29];
    const float* mw1 = (const float*)d_in[30];
    const float* mb1 = (const float*)d_in[31];
    const float* mw2 = (const float*)d_in[32];
    const float* mb2 = (const float*)d_in[33];
    const float* mw3 = (const float*)d_in[34];
    const float* mb3 = (const float*)d_in[35];

    // ---------------- workspace carve-up (~156 MB base) --------------------
    char* wp = (char*)d_ws;
    auto carve = [&](size_t bytes) { char* r = wp; wp += (bytes + 255) & ~(size_t)255; return r; };
    unsigned short* R1 = (unsigned short*)carve(40960000);  // featT L0 bf16
    unsigned short* R2 = (unsigned short*)carve(40960000);  // sem/attn | q/scores/aw
    unsigned short* R3 = (unsigned short*)carve(40960000);  // emb | qnT/wcT
    float* ctxg = (float*)carve(5242880);
    float* gbuf = (float*)carve(5242880);
    float* g2   = (float*)carve(5242880);
    float* h1   = (float*)carve(1310720);
    float* h2   = (float*)carve(1310720);
    unsigned short* lcnT = (unsigned short*)carve(1048576);
    unsigned short* lcB  = (unsigned short*)carve(1048576);
    float* lcr  = (float*)carve(20480);
    float* scl  = (float*)carve(320000);
    float* SK   = (float*)carve(5120000);                   // split-K scratch
    unsigned short* wbuf = (unsigned short*)carve(7500000); // all weights bf16

    // Optional: persist featT for levels 1-3 across phases (skips transCvtF
    // re-runs in phase 2).  Falls back to the shared-R1 layout otherwise.
    unsigned short* featP[4];
    featP[0] = R1;
    {
        size_t f1 = 2UL * BB * 2500 * 512;
        size_t f2 = 2UL * BB * 625 * 1024;
        size_t f3 = 2UL * BB * 169 * 2048;
        size_t used = (size_t)(wp - (char*)d_ws);
        bool ok = (used + f1 + f2 + f3 + (1u << 20) + 4096) <= ws_size;
        if (ok) {
            featP[1] = (unsigned short*)carve(f1);
            featP[2] = (unsigned short*)carve(f2);
            featP[3] = (unsigned short*)carve(f3);
            carve(1u << 20);   // over-read guard for direct-to-LDS staging
        } else {
            featP[1] = featP[2] = featP[3] = R1;
        }
    }
    bool persist = (featP[1] != R1);

    float* outp = (float*)d_out;

    // ---------------- fused weight conversion ------------------------------
    // Per level: sem, emb (contiguous -> stacked [sem;emb]), q, then
    // interleaved [w_out | w_res] rows of length CC+ci for the fused out GEMM.
    CvtJobs jobs;
    unsigned short *wsemB[4], *wqB[4], *woutresB[4];
    long woff = 0; int maxn = 0, jx = 0;
    auto addJob = [&](const float* s, int n, int K, int ld, int colOff, long off) {
        jobs.j[jx].src = s; jobs.j[jx].off = off; jobs.j[jx].n = n;
        jobs.j[jx].K = K; jobs.j[jx].ld = ld; jobs.j[jx].colOff = colOff;
        if (n > maxn) maxn = n;
        ++jx;
    };
    for (int i = 0; i < 4; ++i) {
        int ci = CI[i], ni = NI[i];
        wsemB[i] = wbuf + woff;
        addJob(w_sem[i], ni * ci, ci, ci, 0, woff);  woff += ni * ci;
        addJob(w_emb[i], CC * ci, ci, ci, 0, woff);  woff += CC * ci;   // stacked after sem
        wqB[i] = wbuf + woff;
        addJob(w_q[i],   CC * ci, ci, ci, 0, woff);  woff += CC * ci;
        woutresB[i] = wbuf + woff;
        addJob(w_out[i], CC * CC, CC, CC + ci, 0,  woff);
        addJob(w_res[i], CC * ci, ci, CC + ci, CC, woff);
        woff += (long)CC * (CC + ci);
    }

    cvtAllK<<<dim3((maxn + 255) / 256, 20), 256, 0, stream>>>(jobs, wbuf);

    auto mgFull = [&](const unsigned short* A, long sA, int lda,
                      const unsigned short* B1, long sB1, int ldb1,
                      const unsigned short* B2, long sB2, int ldb2, int Kb,
                      void* Cp, long sC, int ldc, long offC,
                      int M, int N, int K, int mode, int kc,
                      void* C2, long sC2, int ldc2, long offC2, int M1, int mode2) {
        if (kc < 1) kc = 1;
        int kLen = ((K + kc - 1) / kc + 31) & ~31;
        int kcc = (K + kLen - 1) / kLen;
        int gxn = (N + 127) / 128, gym = (M + 127) / 128;
        dim3 g((unsigned)(gxn * gym * BB * kcc));
        mfmaGemm<<<g, 256, 0, stream>>>(A, sA, lda, B1, sB1, ldb1,
                                        B2, sB2, ldb2, Kb,
                                        Cp, sC, ldc, offC, M, N, K, kcc, kLen, mode,
                                        gxn, gym, C2, sC2, ldc2, offC2, M1, mode2);
    };
    auto mg = [&](const unsigned short* A, long sA, int lda,
                  const unsigned short* Bp, long sB, int ldb,
                  void* Cp, long sC, int ldc, long offC,
                  int M, int N, int K, int mode, int kc) {
        mgFull(A, sA, lda, Bp, sB, ldb, nullptr, 0, 8, K,
               Cp, sC, ldc, offC, M, N, K, mode, kc,
               nullptr, 0, 1, 0, M, 0);
    };
    // projection W(M,K)bf16 @ featT(N,K) -> dst contiguous (B,M,N), f16/bf16
    auto projTo = [&](const unsigned short* Wbf, int K, const unsigned short* Xt, long sXt,
                      unsigned short* dst, int M, int N, int fmode) {
        int blocks = ((M + 127) / 128) * ((N + 127) / 128) * BB;
        if (blocks >= 256 || K < 512) {
            mg(Wbf, 0, K, Xt, sXt, K, dst, (long)M * N, N, 0, M, N, K, fmode, 1);
        } else {
            int kc = (256 + blocks - 1) / blocks;
            hipMemsetAsync(SK, 0, (size_t)BB * M * N * 4, stream);
            mg(Wbf, 0, K, Xt, sXt, K, SK, (long)M * N, N, 0, M, N, K, 2, kc);
            long tot = (long)BB * M * N;
            cvtOut<<<dim3((unsigned)((tot + 255) / 256)), 256, 0, stream>>>(
                SK, dst, (int)tot, fmode == 3 ? 1 : 0);
        }
    };

    hipMemsetAsync(ctxg, 0, (size_t)BB * CC * GG * 4, stream);

    // ---------------- Phase 1: per-level attention -> ctxg -----------------
    for (int i = 0; i < 4; ++i) {
        int ci = CI[i], ni = NI[i], hw = HWs[i];
        unsigned short* fT = featP[i];
        transCvtF<<<dim3((hw + 31) / 32, (ci + 31) / 32, BB), 256, 0, stream>>>(
            feat[i], (long)ci * hw, ci, hw, fT, (long)hw * ci, nullptr, 0);
        posStatsT<<<dim3(hw, BB), 256, 0, stream>>>(fT, scl, ci, hw, sqrtf((float)ci));
        if (i < 2) {
            // stacked [sem ; emb]: one featT read -> sem f16 (R2) + emb bf16 (R3)
            mgFull(wsemB[i], 0, ci, fT, (long)hw * ci, ci, nullptr, 0, 8, ci,
                   R2, (long)ni * hw, hw, 0,
                   ni + CC, hw, ci, 3, 1,
                   R3, (long)CC * hw, hw, 0, ni, 4);
        } else {
            projTo(wsemB[i], ci, fT, (long)hw * ci, R2, ni, hw, 3);
            projTo(wsemB[i] + (long)ni * ci, ci, fT, (long)hw * ci, R3, CC, hw, 4);
        }
        enScale<<<dim3((hw + 255) / 256, BB), 256, 0, stream>>>(R2, scl, ni, hw);
        // attn = softmax_p(sem*scl) in place over R2 (bf16 out)
        softmaxHW<<<dim3(ni, BB), 256, 0, stream>>>(R2, scl, ni, hw);
        // ctx += emb @ attn^T -> ctxg (atomic, split-K when skinny)
        {
            int blocks = ((CC + 127) / 128) * ((ni + 127) / 128) * BB;
            int kc = (blocks < 256 && hw >= 512) ? (256 + blocks - 1) / blocks : 1;
            mg(R3, (long)CC * hw, hw, R2, (long)ni * hw, hw,
               ctxg, (long)CC * GG, GG, PTR[i], CC, ni, hw, 2, kc);
        }
    }

    // ---------------- GCN per level (fused across levels) ------------------
    {
        dim3 gl(GG / 64, 1, BB);
        gemmA<<<gl, 256, 0, stream>>>(gw1, 0, ctxg, (long)CC * GG, GG, 0,
                                      h1, (long)64 * GG, GG, 0, gb1,
                                      nullptr, 0, 0, 0, 64, CC, GG, 1, 0,
                                      1, (long)64 * CC, 64);
        gemmA<<<gl, 256, 0, stream>>>(gw2, 0, h1, (long)64 * GG, GG, 0,
                                      h2, (long)64 * GG, GG, 0, gb2,
                                      nullptr, 0, 0, 0, 64, 64, GG, 1, 0,
                                      1, (long)64 * 64, 64);
        dim3 gl2(GG / 64, CC / 64, BB);
        gemmA<<<gl2, 256, 0, stream>>>(gw3, 0, h2, (long)64 * GG, GG, 0,
                                       gbuf, (long)CC * GG, GG, 0, gb3,
                                       ctxg, (long)CC * GG, GG, 0, CC, 64, GG, 0, 0,
                                       1, (long)CC * 64, CC);
    }
    // ---------------- Master GCN + residual -> g2 --------------------------
    {
        dim3 gl(GG / 64, 1, BB);
        gemmA<<<gl, 256, 0, stream>>>(mw1, 0, gbuf, (long)CC * GG, GG, 0,
                                      h1, (long)64 * GG, GG, 0, mb1,
                                      nullptr, 0, 0, 0, 64, CC, GG, 1, 0, 0, 0, 0);
        gemmA<<<gl, 256, 0, stream>>>(mw2, 0, h1, (long)64 * GG, GG, 0,
                                      h2, (long)64 * GG, GG, 0, mb2,
                                      nullptr, 0, 0, 0, 64, 64, GG, 1, 0, 0, 0, 0);
        dim3 gl2(GG / 64, CC / 64, BB);
        gemmA<<<gl2, 256, 0, stream>>>(mw3, 0, h2, (long)64 * GG, GG, 0,
                                       g2, (long)CC * GG, GG, 0, mb3,
                                       gbuf, (long)CC * GG, GG, 0, CC, 64, GG, 0, 0, 0, 0, 0);
    }

    lcRnorm<<<dim3(3, BB), 256, 0, stream>>>(g2, lcr);

    // ---------------- Phase 2: per-level read-out attention ----------------
    for (int i = 0; i < 4; ++i) {
        int ci = CI[i], ni = NI[i], hw = HWs[i];
        long tot = (long)BB * ni * CC;
        buildLc<<<dim3((unsigned)((tot + 255) / 256)), 256, 0, stream>>>(
            g2, lcr, lcnT, lcB, ni, PTR[i]);
        unsigned short* fT = featP[i];
        if (!persist)
            transCvtF<<<dim3((hw + 31) / 32, (ci + 31) / 32, BB), 256, 0, stream>>>(
                feat[i], (long)ci * hw, ci, hw, fT, (long)hw * ci, nullptr, 0);
        // q -> R2 f16
        projTo(wqB[i], ci, fT, (long)hw * ci, R2, CC, hw, 3);
        qNormCol<<<dim3((hw + 255) / 256, BB), 256, 0, stream>>>(R2, scl, hw);
        // qnT = transpose(q)*scl -> R3 bf16 (hw, 256)
        transCvtH<<<dim3((hw + 31) / 32, (CC + 31) / 32, BB), 256, 0, stream>>>(
            R2, (long)CC * hw, CC, hw, R3, (long)hw * CC, scl, hw);
        // scores = qnT @ lcnT^T -> R2 f16 (hw, ni)   (q dead)
        mg(R3, (long)hw * CC, CC, lcnT, (long)ni * CC, CC,
           R2, (long)hw * ni, ni, 0, hw, ni, CC, 3, 1);
        // aw = softmax_n in place over R2 (bf16 out)
        softmaxN<<<dim3((hw + 3) / 4, BB), 256, 0, stream>>>(R2, hw, ni);
        // wcT = aw @ lcB^T -> R3 bf16 (hw, 256)   (qnT dead)
        mg(R2, (long)hw * ni, ni, lcB, (long)CC * ni, ni,
           R3, (long)hw * CC, CC, 0, hw, CC, ni, 4, 1);
        // out = [w_out | w_res] @ [wcT ; featT]  (segmented K, single write)
        {
            int K = CC + ci;
            int blocks = ((CC + 127) / 128) * ((hw + 127) / 128) * BB;
            if (blocks >= 256) {
                mgFull(woutresB[i], 0, K, R3, (long)hw * CC, CC,
                       fT, (long)hw * ci, ci, CC,
                       outp, (long)CC * hw, hw, OUTOFF[i], CC, hw, K, 0, 1,
                       nullptr, 0, 1, 0, CC, 0);
            } else {
                int kc = (256 + blocks - 1) / blocks;
                hipMemsetAsync(outp + OUTOFF[i], 0, (size_t)BB * CC * hw * 4, stream);
                mgFull(woutresB[i], 0, K, R3, (long)hw * CC, CC,
                       fT, (long)hw * ci, ci, CC,
                       outp, (long)CC * hw, hw, OUTOFF[i], CC, hw, K, 2, kc,
                       nullptr, 0, 1, 0, CC, 0);
            }
        }
    }
}

// Round 4
// 1927.605 us; speedup vs baseline: 1.1439x; 1.0234x over previous
//
#include <hip/hip_runtime.h>
#include <math.h>

// ---------------------------------------------------------------------------
// MultiLevelGlobalContext — bf16 MFMA + global_load_lds + counted-vmcnt
// 3-buffer pipeline with ASM ds_read fragments (no compiler vmcnt drains),
// hoisted staging pointers, LDS XOR-swizzle, XCD swizzle, stacked dual-output
// GEMMs + segmented-K fused output GEMM.
// Levels: ci={256,512,1024,2048}, hw={10000,2500,625,169}, ni={256,192,128,64}
// B=8, C=256, G=640.
// ---------------------------------------------------------------------------

#define BB 8
#define CC 256
#define GG 640

typedef __attribute__((ext_vector_type(8))) short short8;
typedef __attribute__((ext_vector_type(4))) float f32x4;
typedef __attribute__((ext_vector_type(4))) int i32x4;

__device__ __forceinline__ unsigned short f2bf(float f) {
    unsigned int u = __float_as_uint(f);
    u += 0x7fffu + ((u >> 16) & 1u);
    return (unsigned short)(u >> 16);
}
__device__ __forceinline__ float bf2f(unsigned short h) {
    return __uint_as_float(((unsigned int)h) << 16);
}
__device__ __forceinline__ float h2f(unsigned short h) {
    union { unsigned short u; _Float16 x; } cv; cv.u = h; return (float)cv.x;
}
__device__ __forceinline__ unsigned short f2h(float f) {
    union { unsigned short u; _Float16 x; } cv; cv.x = (_Float16)f; return cv.u;
}

// async global -> LDS, 16B per lane (wave-uniform LDS base + lane*16 layout)
__device__ __forceinline__ void glds16(const unsigned short* g, unsigned short* l) {
    __builtin_amdgcn_global_load_lds(
        (const __attribute__((address_space(1))) void*)g,
        (__attribute__((address_space(3))) void*)l, 16, 0, 0);
}

// LDS k-segment swizzle: logical kseg at (row,phys) is phys ^ f(row).
// f(row)=(row>>1)&3 makes the fragment-read slot (4*row + kq^f) mod 8 a
// bijection per 8 rows -> exact 2-way bank aliasing (free on CDNA4).
__device__ __forceinline__ int swz(int row, int seg) { return seg ^ ((row >> 1) & 3); }

// ===================== bf16 MFMA GEMM: C[b] = A(M,K) @ B(N,K)^T =============
// A, B bf16 (ushort), K contiguous.  Direct-to-LDS, 3-buffer depth-2 pipeline
// with counted vmcnt; fragment reads are inline-asm ds_read_b128 so the
// compiler's alias-driven vmcnt(0) drain cannot re-serialize the pipeline
// (rule #18: lgkmcnt(0)+sched_barrier(0) after).  Fallback 2-buffer drain
// loop for unaligned/tail chunks.
// Segmented B: k<Kb reads B1, k>=Kb reads B2 (col k-Kb).
// Segmented C: rows [0,M1) -> C/mode, rows [M1,M) -> C2/mode2.
// modes: 0 store f32, 1 accum f32, 2 atomicAdd f32, 3 store f16, 4 store bf16
__global__ __launch_bounds__(256) void mfmaGemm(
    const unsigned short* __restrict__ A, long sA, int lda,
    const unsigned short* __restrict__ B, long sB, int ldb,
    const unsigned short* __restrict__ B2p, long sB2, int ldb2, int Kb,
    void* __restrict__ C, long sC, int ldc, long offC,
    int M, int N, int K, int kChunks, int kChunkLen, int mode,
    int gxn, int gym,
    void* __restrict__ C2, long sC2, int ldc2, long offC2, int M1, int mode2)
{
    __shared__ __align__(16) unsigned short As[3][128 * 32];
    __shared__ __align__(16) unsigned short Bs[3][128 * 32];

    // ---- XCD-chunked bijective swizzle (each XCD gets a contiguous chunk) --
    const int nb = (int)gridDim.x;
    int orig = (int)blockIdx.x;
    int xcd = orig & 7, idx = orig >> 3;
    int q8 = nb >> 3, r8 = nb & 7;
    int wg = (xcd < r8) ? (xcd * (q8 + 1) + idx)
                        : (r8 * (q8 + 1) + (xcd - r8) * q8 + idx);
    int mb, nbk, z;
    if (N >= M) { mb = wg % gym; int t = wg / gym; nbk = t % gxn; z = t / gxn; }
    else        { nbk = wg % gxn; int t = wg / gxn; mb = t % gym; z = t / gym; }

    const int b = z / kChunks, chunk = z - b * kChunks;
    const int kbeg = chunk * kChunkLen;
    const int kend = min(K, kbeg + kChunkLen);
    const int m0 = mb * 128, n0 = nbk * 128;

    const unsigned short* Ab  = A + (long)b * sA;
    const unsigned short* Bb  = B + (long)b * sB;
    const unsigned short* Bb2 = B2p ? (B2p + (long)b * sB2) : nullptr;

    const int tid = threadIdx.x;
    const int row = tid >> 2, seg = tid & 3;      // staging: row 0..63, 8-elem seg
    const int wave = tid >> 6, lane = tid & 63;
    const int wm = (wave & 1) * 64, wn = (wave >> 1) * 64;
    const int lm = lane & 15, kq = lane >> 4;

    const bool okA  = ((lda  & 7) == 0) && ((((size_t)Ab)  & 15) == 0);
    const bool okB  = ((ldb  & 7) == 0) && ((((size_t)Bb)  & 15) == 0);
    const bool okB2 = Bb2 && ((ldb2 & 7) == 0) && ((((size_t)Bb2) & 15) == 0);

    f32x4 acc[4][4];
    #pragma unroll
    for (int i = 0; i < 4; ++i)
        #pragma unroll
        for (int j = 0; j < 4; ++j) acc[i][j] = (f32x4){0.f, 0.f, 0.f, 0.f};

    // -------- hoisted LDS byte addresses for asm fragment reads ------------
    const int ldsOff = row * 32 + seg * 8;        // staging element offset
    unsigned asBase = (unsigned)(unsigned long long)
        (__attribute__((address_space(3))) unsigned short*)&As[0][0];
    unsigned bsBase = (unsigned)(unsigned long long)
        (__attribute__((address_space(3))) unsigned short*)&Bs[0][0];
    unsigned aAddr[4], bAddr[4];
    #pragma unroll
    for (int mt = 0; mt < 4; ++mt) {
        int rA = wm + mt * 16 + lm;
        aAddr[mt] = asBase + (unsigned)((rA * 32 + swz(rA, kq) * 8) * 2);
    }
    #pragma unroll
    for (int nt = 0; nt < 4; ++nt) {
        int rB = wn + nt * 16 + lm;
        bAddr[nt] = bsBase + (unsigned)((rB * 32 + swz(rB, kq) * 8) * 2);
    }

    // fragment read (asm, invisible to waitcnt pass) + 16 MFMA from buf cur
    auto computeAsm = [&](int cur) {
        unsigned bo = (unsigned)cur * 8192u;
        i32x4 fa0, fa1, fa2, fa3, fb0, fb1, fb2, fb3;
        asm volatile("ds_read_b128 %0, %1" : "=v"(fa0) : "v"(aAddr[0] + bo));
        asm volatile("ds_read_b128 %0, %1" : "=v"(fa1) : "v"(aAddr[1] + bo));
        asm volatile("ds_read_b128 %0, %1" : "=v"(fa2) : "v"(aAddr[2] + bo));
        asm volatile("ds_read_b128 %0, %1" : "=v"(fa3) : "v"(aAddr[3] + bo));
        asm volatile("ds_read_b128 %0, %1" : "=v"(fb0) : "v"(bAddr[0] + bo));
        asm volatile("ds_read_b128 %0, %1" : "=v"(fb1) : "v"(bAddr[1] + bo));
        asm volatile("ds_read_b128 %0, %1" : "=v"(fb2) : "v"(bAddr[2] + bo));
        asm volatile("ds_read_b128 %0, %1" : "=v"(fb3) : "v"(bAddr[3] + bo));
        asm volatile("s_waitcnt lgkmcnt(0)" ::: "memory");
        __builtin_amdgcn_sched_barrier(0);   // rule #18: pin MFMA after the wait
        short8 af[4] = { *(short8*)&fa0, *(short8*)&fa1, *(short8*)&fa2, *(short8*)&fa3 };
        short8 bf_[4] = { *(short8*)&fb0, *(short8*)&fb1, *(short8*)&fb2, *(short8*)&fb3 };
        #pragma unroll
        for (int mt = 0; mt < 4; ++mt)
            #pragma unroll
            for (int nt = 0; nt < 4; ++nt)
                acc[mt][nt] = __builtin_amdgcn_mfma_f32_16x16x32_bf16(
                    af[mt], bf_[nt], acc[mt][nt], 0, 0, 0);
    };

    // slow: reg roundtrip with zero-fill (unaligned ld / k-tail / row OOB)
    auto stageS = [&](const unsigned short* Pb, int ld, int lim, int o0,
                      unsigned short* LS, int kg, int lend) {
        #pragma unroll
        for (int l = 0; l < 2; ++l) {
            int rf = l * 64 + row;
            int kgg = kg + swz(rf, seg) * 8;
            int krem = lend - kgg;
            int g = o0 + rf;
            uint4 v = make_uint4(0u, 0u, 0u, 0u);
            if (g < lim && krem > 0) {
                const unsigned short* src = Pb + (long)g * ld + kgg;
                if (krem >= 8 && ((((size_t)src) & 15) == 0)) {
                    v = *(const uint4*)src;
                } else {
                    __align__(16) unsigned short tmp[8] = {0,0,0,0,0,0,0,0};
                    int c = krem < 8 ? krem : 8;
                    for (int j = 0; j < c; ++j) tmp[j] = src[j];
                    v = *(const uint4*)tmp;
                }
            }
            *(uint4*)&LS[rf * 32 + seg * 8] = v;
        }
    };
    auto stage = [&](int kg, int buf) {
        bool full = (kg + 32 <= kend);
        if (okA && full) {
            #pragma unroll
            for (int l = 0; l < 2; ++l) {
                int rf = l * 64 + row;
                const unsigned short* src = Ab + (long)(m0 + rf) * lda + kg + swz(rf, seg) * 8;
                glds16(src, &As[buf][rf * 32 + seg * 8]);
            }
        } else stageS(Ab, lda, M, m0, As[buf], kg, kend);
        if (kg < Kb) {
            if (okB && full && kg + 32 <= Kb) {
                #pragma unroll
                for (int l = 0; l < 2; ++l) {
                    int rf = l * 64 + row;
                    const unsigned short* src = Bb + (long)(n0 + rf) * ldb + kg + swz(rf, seg) * 8;
                    glds16(src, &Bs[buf][rf * 32 + seg * 8]);
                }
            } else stageS(Bb, ldb, N, n0, Bs[buf], kg, min(kend, Kb));
        } else {
            int kl = kg - Kb;
            if (okB2 && full) {
                #pragma unroll
                for (int l = 0; l < 2; ++l) {
                    int rf = l * 64 + row;
                    const unsigned short* src = Bb2 + (long)(n0 + rf) * ldb2 + kl + swz(rf, seg) * 8;
                    glds16(src, &Bs[buf][rf * 32 + seg * 8]);
                }
            } else stageS(Bb2, ldb2, N, n0, Bs[buf], kl, kend - Kb);
        }
    };

    // Pipelined path: all-fast staging, K-chunk multiple of 32, segment
    // boundary 32-aligned.  Depth-2 prefetch, counted vmcnt across barriers.
    const bool pipe = okA && (kbeg >= Kb || okB) && (kend <= Kb || okB2 || !B2p) &&
                      (((kend - kbeg) & 31) == 0) && ((Kb & 31) == 0);

    if (pipe) {
        // ---- hoisted per-thread staging pointers (advance 64B per stage) ---
        const int sz0 = swz(row, seg) * 8, sz1 = swz(64 + row, seg) * 8;
        const unsigned short* pA0 = Ab + (long)(m0 + row) * lda + kbeg + sz0;
        const unsigned short* pA1 = Ab + (long)(m0 + 64 + row) * lda + kbeg + sz1;
        const unsigned short* pB0 = nullptr; const unsigned short* pB1 = nullptr;
        const unsigned short* pC0 = nullptr; const unsigned short* pC1 = nullptr;
        if (kbeg < Kb) {
            pB0 = Bb + (long)(n0 + row) * ldb + kbeg + sz0;
            pB1 = Bb + (long)(n0 + 64 + row) * ldb + kbeg + sz1;
        }
        if (Bb2) {
            int c2 = kbeg > Kb ? kbeg - Kb : 0;
            pC0 = Bb2 + (long)(n0 + row) * ldb2 + c2 + sz0;
            pC1 = Bb2 + (long)(n0 + 64 + row) * ldb2 + c2 + sz1;
        }
        int kIss = kbeg;
        auto issueStage = [&](int buf) {
            unsigned short* a0 = &As[buf][ldsOff];
            glds16(pA0, a0); glds16(pA1, a0 + 2048);
            pA0 += 32; pA1 += 32;
            unsigned short* b0 = &Bs[buf][ldsOff];
            if (kIss < Kb) { glds16(pB0, b0); glds16(pB1, b0 + 2048); pB0 += 32; pB1 += 32; }
            else           { glds16(pC0, b0); glds16(pC1, b0 + 2048); pC0 += 32; pC1 += 32; }
            kIss += 32;
        };
        issueStage(0);                          // vm in-flight: 4
        if (kIss < kend) issueStage(1);         // vm in-flight: 8
        int cur = 0;
        for (int k0 = kbeg; k0 < kend; k0 += 32) {
            // own step-k0 loads complete; next step's stay in flight
            if (k0 + 32 < kend) asm volatile("s_waitcnt vmcnt(4)" ::: "memory");
            else                asm volatile("s_waitcnt vmcnt(0)" ::: "memory");
            __builtin_amdgcn_s_barrier();       // all waves' k0 loads done
            __builtin_amdgcn_sched_barrier(0);
            if (kIss < kend) {                  // stage k0+64 into cur+2 (mod 3)
                int nb3 = cur + 2; if (nb3 >= 3) nb3 -= 3;
                issueStage(nb3);
            }
            computeAsm(cur);
            cur = (cur + 1 == 3) ? 0 : cur + 1;
        }
    } else {
        stage(kbeg, 0);
        int cur = 0;
        for (int k0 = kbeg; k0 < kend; k0 += 32) {
            __syncthreads();                   // drains own vmcnt/lgkmcnt
            if (k0 + 32 < kend) stage(k0 + 32, cur ^ 1);
            computeAsm(cur);
            cur ^= 1;
        }
    }

    const long cb1 = (long)b * sC + offC;
    const long cb2 = (long)b * sC2 + offC2;
    #pragma unroll
    for (int mt = 0; mt < 4; ++mt) {
        #pragma unroll
        for (int nt = 0; nt < 4; ++nt) {
            int n_g = n0 + wn + nt * 16 + lm;
            if (n_g >= N) continue;
            #pragma unroll
            for (int r = 0; r < 4; ++r) {
                int m_g = m0 + wm + mt * 16 + kq * 4 + r;
                if (m_g >= M) continue;
                float v = acc[mt][nt][r];
                void* Cp; int md; long cix;
                if (m_g < M1) { Cp = C;  md = mode;  cix = cb1 + (long)m_g * ldc + n_g; }
                else          { Cp = C2; md = mode2; cix = cb2 + (long)(m_g - M1) * ldc2 + n_g; }
                if (md == 0)      ((float*)Cp)[cix] = v;
                else if (md == 1) ((float*)Cp)[cix] += v;
                else if (md == 2) atomicAdd(&((float*)Cp)[cix], v);
                else if (md == 3) ((unsigned short*)Cp)[cix] = f2h(v);
                else              ((unsigned short*)Cp)[cix] = f2bf(v);
            }
        }
    }
}

// ================= fp32 GEMM (GCN layers), with optional per-level fusing ==
__global__ __launch_bounds__(256) void gemmA(
    const float* __restrict__ W, long sW,
    const float* __restrict__ X, long sX, int ldx, long offX,
    float* __restrict__ Cd, long sC, int ldc, long offC,
    const float* __restrict__ bias,
    const float* __restrict__ res, long sR, int ldr, long offR,
    int O, int K, int P, int relu, int accum,
    int lvlFuse, long wStride, int bStride)
{
    __shared__ float Ws[16][64];
    __shared__ float Xs[16][64];
    const int tid = threadIdx.x;
    const int tx = tid & 15;
    const int ty = tid >> 4;
    const int b  = blockIdx.z;
    const int o0 = blockIdx.y * 64;
    const int p0 = blockIdx.x * 64;

    const float* Wp = W;
    const float* bp = bias;
    if (lvlFuse) {
        int lvl = p0 >= 576 ? 3 : p0 >= 448 ? 2 : p0 >= 256 ? 1 : 0;
        Wp += (long)lvl * wStride;
        if (bias) bp += (long)lvl * bStride;
    }
    const float* Wb = Wp + (long)b * sW;
    const float* Xb = X + (long)b * sX + offX;

    float acc[4][4] = {};

    const int wo = tid >> 2;
    const int wk = (tid & 3) * 4;
    const int xp = tid & 63;
    const int xq = tid >> 6;

    for (int k0 = 0; k0 < K; k0 += 16) {
        #pragma unroll
        for (int u = 0; u < 4; ++u) {
            int kk = wk + u;
            float v = 0.f;
            if (o0 + wo < O && k0 + kk < K) v = Wb[(long)(o0 + wo) * K + k0 + kk];
            Ws[kk][wo] = v;
        }
        #pragma unroll
        for (int u = 0; u < 4; ++u) {
            int kk = xq * 4 + u;
            float v = 0.f;
            if (p0 + xp < P && k0 + kk < K) v = Xb[(long)(k0 + kk) * ldx + (p0 + xp)];
            Xs[kk][xp] = v;
        }
        __syncthreads();
        #pragma unroll
        for (int kk = 0; kk < 16; ++kk) {
            float4 wv = *(const float4*)&Ws[kk][ty * 4];
            float4 xv = *(const float4*)&Xs[kk][tx * 4];
            float wa[4] = {wv.x, wv.y, wv.z, wv.w};
            float xa[4] = {xv.x, xv.y, xv.z, xv.w};
            #pragma unroll
            for (int i = 0; i < 4; ++i)
                #pragma unroll
                for (int j = 0; j < 4; ++j)
                    acc[i][j] += wa[i] * xa[j];
        }
        __syncthreads();
    }

    #pragma unroll
    for (int i = 0; i < 4; ++i) {
        int o = o0 + ty * 4 + i;
        if (o >= O) continue;
        #pragma unroll
        for (int j = 0; j < 4; ++j) {
            int p = p0 + tx * 4 + j;
            if (p >= P) continue;
            float v = acc[i][j];
            if (bias) v += bp[o];
            if (relu) v = fmaxf(v, 0.f);
            if (res)  v += res[(long)b * sR + offR + (long)o * ldr + p];
            long ci_ = (long)b * sC + offC + (long)o * ldc + p;
            if (accum) Cd[ci_] += v; else Cd[ci_] = v;
        }
    }
}

// =================== transpose+convert: dst[c][r] = src[r][c]*scale[c] =====
__global__ __launch_bounds__(256) void transCvtF(
    const float* __restrict__ src, long sS, int R, int Cc,
    unsigned short* __restrict__ dst, long sD,
    const float* __restrict__ scale, long sScale)
{
    __shared__ float tile[32][33];
    int b = blockIdx.z;
    int r0 = blockIdx.y * 32, c0 = blockIdx.x * 32;
    const float* sb = src + (long)b * sS;
    unsigned short* db = dst + (long)b * sD;
    int tr = threadIdx.x >> 5, tc = threadIdx.x & 31;
    #pragma unroll
    for (int it = 0; it < 4; ++it) {
        int r = r0 + tr + it * 8, c = c0 + tc;
        tile[tr + it * 8][tc] = (r < R && c < Cc) ? sb[(long)r * Cc + c] : 0.f;
    }
    __syncthreads();
    #pragma unroll
    for (int it = 0; it < 4; ++it) {
        int c = c0 + tr + it * 8;
        int r = r0 + tc;
        if (c < Cc && r < R) {
            float v = tile[tc][tr + it * 8];
            if (scale) v *= scale[(long)b * sScale + c];
            db[(long)c * R + r] = f2bf(v);
        }
    }
}

__global__ __launch_bounds__(256) void transCvtH(
    const unsigned short* __restrict__ src, long sS, int R, int Cc,
    unsigned short* __restrict__ dst, long sD,
    const float* __restrict__ scale, long sScale)
{
    __shared__ float tile[32][33];
    int b = blockIdx.z;
    int r0 = blockIdx.y * 32, c0 = blockIdx.x * 32;
    const unsigned short* sb = src + (long)b * sS;
    unsigned short* db = dst + (long)b * sD;
    int tr = threadIdx.x >> 5, tc = threadIdx.x & 31;
    #pragma unroll
    for (int it = 0; it < 4; ++it) {
        int r = r0 + tr + it * 8, c = c0 + tc;
        tile[tr + it * 8][tc] = (r < R && c < Cc) ? h2f(sb[(long)r * Cc + c]) : 0.f;
    }
    __syncthreads();
    #pragma unroll
    for (int it = 0; it < 4; ++it) {
        int c = c0 + tr + it * 8;
        int r = r0 + tc;
        if (c < Cc && r < R) {
            float v = tile[tc][tr + it * 8];
            if (scale) v *= scale[(long)b * sScale + c];
            db[(long)c * R + r] = f2bf(v);
        }
    }
}

// ====== per-position stats from featT rows ================================
__global__ __launch_bounds__(256) void posStatsT(
    const unsigned short* __restrict__ featT, float* __restrict__ fscale,
    int ci, int hw, float sq)
{
    int b = blockIdx.y, p = blockIdx.x;
    const unsigned short* row = featT + ((long)b * hw + p) * ci;
    float s = 0.f, ss = 0.f;
    for (int c = threadIdx.x; c < ci; c += 256) {
        float v = bf2f(row[c]); s += v; ss += v * v;
    }
    __shared__ float rs[256], rss[256];
    int tid = threadIdx.x;
    rs[tid] = s; rss[tid] = ss; __syncthreads();
    for (int st = 128; st > 0; st >>= 1) {
        if (tid < st) { rs[tid] += rs[tid + st]; rss[tid] += rss[tid + st]; }
        __syncthreads();
    }
    if (tid == 0)
        fscale[(long)b * hw + p] = rs[0] / fmaxf(sqrtf(rss[0]), 1e-12f) * sq;
}

// ==== scale[b,p] = fscale[b,p] / max(||sem[b,:,p]||,eps)  (sem f16) ========
__global__ void enScale(const unsigned short* __restrict__ sem, float* __restrict__ fscale,
                        int ni, int hw)
{
    int b = blockIdx.y;
    int p = blockIdx.x * 256 + threadIdx.x;
    if (p >= hw) return;
    const unsigned short* sb = sem + (long)b * ni * hw + p;
    float ss = 0.f;
    for (int n = 0; n < ni; ++n) { float v = h2f(sb[(long)n * hw]); ss += v * v; }
    fscale[(long)b * hw + p] = fscale[(long)b * hw + p] / fmaxf(sqrtf(ss), 1e-12f);
}

// ==== softmax over p: buf holds sem f16 in, attn bf16 out (IN PLACE) =======
__global__ __launch_bounds__(256) void softmaxHW(
    unsigned short* buf, const float* __restrict__ scale, int ni, int hw)
{
    int b = blockIdx.y, n = blockIdx.x;
    unsigned short* row = buf + ((long)b * ni + n) * hw;
    const float* sc = scale + (long)b * hw;
    __shared__ float red[256];
    int tid = threadIdx.x;

    float m = -1e30f;
    for (int p = tid; p < hw; p += 256) m = fmaxf(m, h2f(row[p]) * sc[p]);
    red[tid] = m; __syncthreads();
    for (int s = 128; s > 0; s >>= 1) {
        if (tid < s) red[tid] = fmaxf(red[tid], red[tid + s]);
        __syncthreads();
    }
    m = red[0]; __syncthreads();

    float sum = 0.f;
    for (int p = tid; p < hw; p += 256) sum += __expf(h2f(row[p]) * sc[p] - m);
    red[tid] = sum; __syncthreads();
    for (int s = 128; s > 0; s >>= 1) {
        if (tid < s) red[tid] += red[tid + s];
        __syncthreads();
    }
    float inv = 1.0f / red[0];

    for (int p = tid; p < hw; p += 256) {
        float v = __expf(h2f(row[p]) * sc[p] - m) * inv;   // read then write
        row[p] = f2bf(v);
    }
}

// ==== softmax over n: buf f16 in, bf16 out (IN PLACE) ======================
__global__ void softmaxN(unsigned short* buf, int hw, int ni)
{
    int b = blockIdx.y;
    int wav = threadIdx.x >> 6, lane = threadIdx.x & 63;
    int p = blockIdx.x * 4 + wav;
    if (p >= hw) return;
    unsigned short* row = buf + ((long)b * hw + p) * ni;
    float m = -1e30f;
    for (int n = lane; n < ni; n += 64) m = fmaxf(m, h2f(row[n]));
    for (int off = 32; off > 0; off >>= 1) m = fmaxf(m, __shfl_xor(m, off));
    float s = 0.f;
    for (int n = lane; n < ni; n += 64) s += __expf(h2f(row[n]) - m);
    for (int off = 32; off > 0; off >>= 1) s += __shfl_xor(s, off);
    float inv = 1.f / s;
    for (int n = lane; n < ni; n += 64) {
        float v = __expf(h2f(row[n]) - m) * inv;
        row[n] = f2bf(v);
    }
}

// ==== lcr[b,col] = 1/max(||g2[b,:,col]||,eps) ==============================
__global__ void lcRnorm(const float* __restrict__ g2, float* __restrict__ lcr)
{
    int b = blockIdx.y;
    int col = blockIdx.x * 256 + threadIdx.x;
    if (col >= GG) return;
    const float* gb = g2 + (long)b * CC * GG + col;
    float ss = 0.f;
    for (int o = 0; o < CC; ++o) { float v = gb[o * GG]; ss += v * v; }
    lcr[b * GG + col] = 1.f / fmaxf(sqrtf(ss), 1e-12f);
}

// ==== lcnT[b,n,o] (normalized) + lcB[b,o,n] (raw), both bf16 ===============
__global__ void buildLc(const float* __restrict__ g2, const float* __restrict__ lcr,
                        unsigned short* __restrict__ lcnT, unsigned short* __restrict__ lcB,
                        int ni, int ptr)
{
    long t = (long)blockIdx.x * 256 + threadIdx.x;
    if (t >= (long)BB * ni * CC) return;
    int o = (int)(t & (CC - 1));
    long r = t >> 8;
    int n = (int)(r % ni);
    int b = (int)(r / ni);
    float raw = g2[(long)b * CC * GG + (long)o * GG + ptr + n];
    lcnT[t] = f2bf(raw * lcr[b * GG + ptr + n]);
    lcB[((long)b * CC + o) * ni + n] = f2bf(raw);
}

// ==== per-position 1/||q[:,p]|| (q f16, CC rows) ===========================
__global__ void qNormCol(const unsigned short* __restrict__ q, float* __restrict__ scl, int hw)
{
    int b = blockIdx.y;
    int p = blockIdx.x * 256 + threadIdx.x;
    if (p >= hw) return;
    const unsigned short* qb = q + (long)b * CC * hw + p;
    float ss = 0.f;
    for (int o = 0; o < CC; ++o) { float v = h2f(qb[(long)o * hw]); ss += v * v; }
    scl[(long)b * hw + p] = 1.f / fmaxf(sqrtf(ss), 1e-12f);
}

// ==== fused weight conversion (20 jobs, strided dest for interleaving) =====
struct CvtJob { const float* src; long off; int n; int K; int ld; int colOff; };
struct CvtJobs { CvtJob j[20]; };
__global__ void cvtAllK(CvtJobs jobs, unsigned short* __restrict__ dst)
{
    const CvtJob J = jobs.j[blockIdx.y];
    int t = blockIdx.x * 256 + threadIdx.x;
    if (t < J.n) {
        int r = t / J.K, c = t - r * J.K;
        dst[J.off + (long)r * J.ld + J.colOff + c] = f2bf(J.src[t]);
    }
}

// ==== split-K tail convert: fp32 -> f16/bf16 ===============================
__global__ void cvtOut(const float* __restrict__ src, unsigned short* __restrict__ dst,
                       int n, int toF16)
{
    int i = blockIdx.x * 256 + threadIdx.x;
    if (i >= n) return;
    float v = src[i];
    dst[i] = toF16 ? f2h(v) : f2bf(v);
}

// ===========================================================================
extern "C" void kernel_launch(void* const* d_in, const int* in_sizes, int n_in,
                              void* d_out, int out_size, void* d_ws, size_t ws_size,
                              hipStream_t stream)
{
    (void)n_in; (void)out_size;
    static const int  CI[4]  = {256, 512, 1024, 2048};
    static const int  NI[4]  = {256, 192, 128, 64};
    static const int  HWs[4] = {10000, 2500, 625, 169};
    static const int  PTR[4] = {0, 256, 448, 576};
    static const long OUTOFF[4] = {0, 20480000L, 25600000L, 26880000L};

    const float* feat[4];
    for (int i = 0; i < 4; ++i) feat[i] = (const float*)d_in[i];

    const float *w_sem[4], *w_emb[4], *w_q[4], *w_out[4], *w_res[4];
    bool grouped = (in_sizes[5] == 192 * 512);
    for (int i = 0; i < 4; ++i) {
        if (grouped) {
            w_sem[i] = (const float*)d_in[4 + i];
            w_emb[i] = (const float*)d_in[8 + i];
            w_q[i]   = (const float*)d_in[12 + i];
            w_out[i] = (const float*)d_in[16 + i];
            w_res[i] = (const float*)d_in[20 + i];
        } else {
            int base = 4 + 5 * i;
            w_sem[i] = (const float*)d_in[base + 0];
            w_emb[i] = (const float*)d_in[base + 1];
            w_q[i]   = (const float*)d_in[base + 2];
            w_out[i] = (const float*)d_in[base + 3];
            w_res[i] = (const float*)d_in[base + 4];
        }
    }
    const float* gw1 = (const float*)d_in[24];
    const float* gb1 = (const float*)d_in[25];
    const float* gw2 = (const float*)d_in[26];
    const float* gb2 = (const float*)d_in[27];
    const float* gw3 = (const float*)d_in[28];
    const float* gb3 = (const float*)d_in[29];
    const float* mw1 = (const float*)d_in[30];
    const float* mb1 = (const float*)d_in[31];
    const float* mw2 = (const float*)d_in[32];
    const float* mb2 = (const float*)d_in[33];
    const float* mw3 = (const float*)d_in[34];
    const float* mb3 = (const float*)d_in[35];

    // ---------------- workspace carve-up (~156 MB base) --------------------
    char* wp = (char*)d_ws;
    auto carve = [&](size_t bytes) { char* r = wp; wp += (bytes + 255) & ~(size_t)255; return r; };
    unsigned short* R1 = (unsigned short*)carve(40960000);  // featT L0 bf16
    unsigned short* R2 = (unsigned short*)carve(40960000);  // sem/attn | q/scores/aw
    unsigned short* R3 = (unsigned short*)carve(40960000);  // emb | qnT/wcT
    float* ctxg = (float*)carve(5242880);
    float* gbuf = (float*)carve(5242880);
    float* g2   = (float*)carve(5242880);
    float* h1   = (float*)carve(1310720);
    float* h2   = (float*)carve(1310720);
    unsigned short* lcnT = (unsigned short*)carve(1048576);
    unsigned short* lcB  = (unsigned short*)carve(1048576);
    float* lcr  = (float*)carve(20480);
    float* scl  = (float*)carve(320000);
    float* SK   = (float*)carve(5120000);                   // split-K scratch
    unsigned short* wbuf = (unsigned short*)carve(7500000); // all weights bf16

    // Optional: persist featT for levels 1-3 across phases (skips transCvtF
    // re-runs in phase 2).  Falls back to the shared-R1 layout otherwise.
    unsigned short* featP[4];
    featP[0] = R1;
    {
        size_t f1 = 2UL * BB * 2500 * 512;
        size_t f2 = 2UL * BB * 625 * 1024;
        size_t f3 = 2UL * BB * 169 * 2048;
        size_t used = (size_t)(wp - (char*)d_ws);
        bool ok = (used + f1 + f2 + f3 + (1u << 20) + 4096) <= ws_size;
        if (ok) {
            featP[1] = (unsigned short*)carve(f1);
            featP[2] = (unsigned short*)carve(f2);
            featP[3] = (unsigned short*)carve(f3);
            carve(1u << 20);   // over-read guard for direct-to-LDS staging
        } else {
            featP[1] = featP[2] = featP[3] = R1;
        }
    }
    bool persist = (featP[1] != R1);

    float* outp = (float*)d_out;

    // ---------------- fused weight conversion ------------------------------
    // Per level: sem, emb (contiguous -> stacked [sem;emb]), q, then
    // interleaved [w_out | w_res] rows of length CC+ci for the fused out GEMM.
    CvtJobs jobs;
    unsigned short *wsemB[4], *wqB[4], *woutresB[4];
    long woff = 0; int maxn = 0, jx = 0;
    auto addJob = [&](const float* s, int n, int K, int ld, int colOff, long off) {
        jobs.j[jx].src = s; jobs.j[jx].off = off; jobs.j[jx].n = n;
        jobs.j[jx].K = K; jobs.j[jx].ld = ld; jobs.j[jx].colOff = colOff;
        if (n > maxn) maxn = n;
        ++jx;
    };
    for (int i = 0; i < 4; ++i) {
        int ci = CI[i], ni = NI[i];
        wsemB[i] = wbuf + woff;
        addJob(w_sem[i], ni * ci, ci, ci, 0, woff);  woff += ni * ci;
        addJob(w_emb[i], CC * ci, ci, ci, 0, woff);  woff += CC * ci;   // stacked after sem
        wqB[i] = wbuf + woff;
        addJob(w_q[i],   CC * ci, ci, ci, 0, woff);  woff += CC * ci;
        woutresB[i] = wbuf + woff;
        addJob(w_out[i], CC * CC, CC, CC + ci, 0,  woff);
        addJob(w_res[i], CC * ci, ci, CC + ci, CC, woff);
        woff += (long)CC * (CC + ci);
    }

    cvtAllK<<<dim3((maxn + 255) / 256, 20), 256, 0, stream>>>(jobs, wbuf);

    auto mgFull = [&](const unsigned short* A, long sA, int lda,
                      const unsigned short* B1, long sB1, int ldb1,
                      const unsigned short* B2, long sB2, int ldb2, int Kb,
                      void* Cp, long sC, int ldc, long offC,
                      int M, int N, int K, int mode, int kc,
                      void* C2, long sC2, int ldc2, long offC2, int M1, int mode2) {
        if (kc < 1) kc = 1;
        int kLen = ((K + kc - 1) / kc + 31) & ~31;
        int kcc = (K + kLen - 1) / kLen;
        int gxn = (N + 127) / 128, gym = (M + 127) / 128;
        dim3 g((unsigned)(gxn * gym * BB * kcc));
        mfmaGemm<<<g, 256, 0, stream>>>(A, sA, lda, B1, sB1, ldb1,
                                        B2, sB2, ldb2, Kb,
                                        Cp, sC, ldc, offC, M, N, K, kcc, kLen, mode,
                                        gxn, gym, C2, sC2, ldc2, offC2, M1, mode2);
    };
    auto mg = [&](const unsigned short* A, long sA, int lda,
                  const unsigned short* Bp, long sB, int ldb,
                  void* Cp, long sC, int ldc, long offC,
                  int M, int N, int K, int mode, int kc) {
        mgFull(A, sA, lda, Bp, sB, ldb, nullptr, 0, 8, K,
               Cp, sC, ldc, offC, M, N, K, mode, kc,
               nullptr, 0, 1, 0, M, 0);
    };
    // projection W(M,K)bf16 @ featT(N,K) -> dst contiguous (B,M,N), f16/bf16
    auto projTo = [&](const unsigned short* Wbf, int K, const unsigned short* Xt, long sXt,
                      unsigned short* dst, int M, int N, int fmode) {
        int blocks = ((M + 127) / 128) * ((N + 127) / 128) * BB;
        if (blocks >= 256 || K < 512) {
            mg(Wbf, 0, K, Xt, sXt, K, dst, (long)M * N, N, 0, M, N, K, fmode, 1);
        } else {
            int kc = (256 + blocks - 1) / blocks;
            hipMemsetAsync(SK, 0, (size_t)BB * M * N * 4, stream);
            mg(Wbf, 0, K, Xt, sXt, K, SK, (long)M * N, N, 0, M, N, K, 2, kc);
            long tot = (long)BB * M * N;
            cvtOut<<<dim3((unsigned)((tot + 255) / 256)), 256, 0, stream>>>(
                SK, dst, (int)tot, fmode == 3 ? 1 : 0);
        }
    };

    hipMemsetAsync(ctxg, 0, (size_t)BB * CC * GG * 4, stream);

    // ---------------- Phase 1: per-level attention -> ctxg -----------------
    for (int i = 0; i < 4; ++i) {
        int ci = CI[i], ni = NI[i], hw = HWs[i];
        unsigned short* fT = featP[i];
        transCvtF<<<dim3((hw + 31) / 32, (ci + 31) / 32, BB), 256, 0, stream>>>(
            feat[i], (long)ci * hw, ci, hw, fT, (long)hw * ci, nullptr, 0);
        posStatsT<<<dim3(hw, BB), 256, 0, stream>>>(fT, scl, ci, hw, sqrtf((float)ci));
        if (i < 2) {
            // stacked [sem ; emb]: one featT read -> sem f16 (R2) + emb bf16 (R3)
            mgFull(wsemB[i], 0, ci, fT, (long)hw * ci, ci, nullptr, 0, 8, ci,
                   R2, (long)ni * hw, hw, 0,
                   ni + CC, hw, ci, 3, 1,
                   R3, (long)CC * hw, hw, 0, ni, 4);
        } else {
            projTo(wsemB[i], ci, fT, (long)hw * ci, R2, ni, hw, 3);
            projTo(wsemB[i] + (long)ni * ci, ci, fT, (long)hw * ci, R3, CC, hw, 4);
        }
        enScale<<<dim3((hw + 255) / 256, BB), 256, 0, stream>>>(R2, scl, ni, hw);
        // attn = softmax_p(sem*scl) in place over R2 (bf16 out)
        softmaxHW<<<dim3(ni, BB), 256, 0, stream>>>(R2, scl, ni, hw);
        // ctx += emb @ attn^T -> ctxg (atomic, split-K when skinny)
        {
            int blocks = ((CC + 127) / 128) * ((ni + 127) / 128) * BB;
            int kc = (blocks < 256 && hw >= 512) ? (256 + blocks - 1) / blocks : 1;
            mg(R3, (long)CC * hw, hw, R2, (long)ni * hw, hw,
               ctxg, (long)CC * GG, GG, PTR[i], CC, ni, hw, 2, kc);
        }
    }

    // ---------------- GCN per level (fused across levels) ------------------
    {
        dim3 gl(GG / 64, 1, BB);
        gemmA<<<gl, 256, 0, stream>>>(gw1, 0, ctxg, (long)CC * GG, GG, 0,
                                      h1, (long)64 * GG, GG, 0, gb1,
                                      nullptr, 0, 0, 0, 64, CC, GG, 1, 0,
                                      1, (long)64 * CC, 64);
        gemmA<<<gl, 256, 0, stream>>>(gw2, 0, h1, (long)64 * GG, GG, 0,
                                      h2, (long)64 * GG, GG, 0, gb2,
                                      nullptr, 0, 0, 0, 64, 64, GG, 1, 0,
                                      1, (long)64 * 64, 64);
        dim3 gl2(GG / 64, CC / 64, BB);
        gemmA<<<gl2, 256, 0, stream>>>(gw3, 0, h2, (long)64 * GG, GG, 0,
                                       gbuf, (long)CC * GG, GG, 0, gb3,
                                       ctxg, (long)CC * GG, GG, 0, CC, 64, GG, 0, 0,
                                       1, (long)CC * 64, CC);
    }
    // ---------------- Master GCN + residual -> g2 --------------------------
    {
        dim3 gl(GG / 64, 1, BB);
        gemmA<<<gl, 256, 0, stream>>>(mw1, 0, gbuf, (long)CC * GG, GG, 0,
                                      h1, (long)64 * GG, GG, 0, mb1,
                                      nullptr, 0, 0, 0, 64, CC, GG, 1, 0, 0, 0, 0);
        gemmA<<<gl, 256, 0, stream>>>(mw2, 0, h1, (long)64 * GG, GG, 0,
                                      h2, (long)64 * GG, GG, 0, mb2,
                                      nullptr, 0, 0, 0, 64, 64, GG, 1, 0, 0, 0, 0);
        dim3 gl2(GG / 64, CC / 64, BB);
        gemmA<<<gl2, 256, 0, stream>>>(mw3, 0, h2, (long)64 * GG, GG, 0,
                                       g2, (long)CC * GG, GG, 0, mb3,
                                       gbuf, (long)CC * GG, GG, 0, CC, 64, GG, 0, 0, 0, 0, 0);
    }

    lcRnorm<<<dim3(3, BB), 256, 0, stream>>>(g2, lcr);

    // ---------------- Phase 2: per-level read-out attention ----------------
    for (int i = 0; i < 4; ++i) {
        int ci = CI[i], ni = NI[i], hw = HWs[i];
        long tot = (long)BB * ni * CC;
        buildLc<<<dim3((unsigned)((tot + 255) / 256)), 256, 0, stream>>>(
            g2, lcr, lcnT, lcB, ni, PTR[i]);
        unsigned short* fT = featP[i];
        if (!persist)
            transCvtF<<<dim3((hw + 31) / 32, (ci + 31) / 32, BB), 256, 0, stream>>>(
                feat[i], (long)ci * hw, ci, hw, fT, (long)hw * ci, nullptr, 0);
        // q -> R2 f16
        projTo(wqB[i], ci, fT, (long)hw * ci, R2, CC, hw, 3);
        qNormCol<<<dim3((hw + 255) / 256, BB), 256, 0, stream>>>(R2, scl, hw);
        // qnT = transpose(q)*scl -> R3 bf16 (hw, 256)
        transCvtH<<<dim3((hw + 31) / 32, (CC + 31) / 32, BB), 256, 0, stream>>>(
            R2, (long)CC * hw, CC, hw, R3, (long)hw * CC, scl, hw);
        // scores = qnT @ lcnT^T -> R2 f16 (hw, ni)   (q dead)
        mg(R3, (long)hw * CC, CC, lcnT, (long)ni * CC, CC,
           R2, (long)hw * ni, ni, 0, hw, ni, CC, 3, 1);
        // aw = softmax_n in place over R2 (bf16 out)
        softmaxN<<<dim3((hw + 3) / 4, BB), 256, 0, stream>>>(R2, hw, ni);
        // wcT = aw @ lcB^T -> R3 bf16 (hw, 256)   (qnT dead)
        mg(R2, (long)hw * ni, ni, lcB, (long)CC * ni, ni,
           R3, (long)hw * CC, CC, 0, hw, CC, ni, 4, 1);
        // out = [w_out | w_res] @ [wcT ; featT]  (segmented K, single write)
        {
            int K = CC + ci;
            int blocks = ((CC + 127) / 128) * ((hw + 127) / 128) * BB;
            if (blocks >= 256) {
                mgFull(woutresB[i], 0, K, R3, (long)hw * CC, CC,
                       fT, (long)hw * ci, ci, CC,
                       outp, (long)CC * hw, hw, OUTOFF[i], CC, hw, K, 0, 1,
                       nullptr, 0, 1, 0, CC, 0);
            } else {
                int kc = (256 + blocks - 1) / blocks;
                hipMemsetAsync(outp + OUTOFF[i], 0, (size_t)BB * CC * hw * 4, stream);
                mgFull(woutresB[i], 0, K, R3, (long)hw * CC, CC,
                       fT, (long)hw * ci, ci, CC,
                       outp, (long)CC * hw, hw, OUTOFF[i], CC, hw, K, 2, kc,
                       nullptr, 0, 1, 0, CC, 0);
            }
        }
    }
}